// Round 2
// 187.064 us; speedup vs baseline: 1.0079x; 1.0079x over previous
//
#include <hip/hip_runtime.h>

typedef unsigned int uint32;
typedef unsigned short u16;
typedef __attribute__((ext_vector_type(8))) short bf16x8;
typedef __attribute__((ext_vector_type(4))) float f32x4;

#define DIM 128
#define MAT (DIM * DIM)
#define GR  2048                 // uint4 granules per 128x128 bf16 plane (32 KB)
#define PLANE 16384              // u16 elements per plane
#define MFMA __builtin_amdgcn_mfma_f32_16x16x32_bf16

// Plane formats:
//  FmtG (global bf16 planes): uint4 granule index = g*128 + row   (g = col/8)
//  LDS standard (chain/pair/final + expm final staging): uint4 idx = row*16 + (g ^ (row&7))
//  LDS subtiled (expm internal, serves BOTH mfma operands):
//    element (r,c) at  ((r>>2)*8 + (c>>4))*64 + (r&3)*16 + (c&15)
//    - row fragment (fixed r, 8 consecutive c): contiguous 16 B  -> ds_read_b128
//    - col fragment (fixed c, consecutive r):   8x ds_read_u16 at elem stride 16
// Core semantic (verified rounds 2/3): with a-frags from PA rows u and b-frags
// from PB rows w,  D[u][w] = sum_k PA[u][k]*PB[w][k]; the f32x4 acc spans 4
// consecutive u at fixed w.  For out = L*R: PA = T(R), PB = N(L), out[w][u]=D.

// ---------------- scalar helpers ----------------
__device__ __forceinline__ u16 f2bf(float x) {
    uint32 u = __float_as_uint(x);
    u += 0x7fffu + ((u >> 16) & 1u);
    return (u16)(u >> 16);
}
__device__ __forceinline__ float bf2f(u16 h) { return __uint_as_float(((uint32)h) << 16); }
__device__ __forceinline__ void split2(float x, u16& a0, u16& a1) {
    a0 = f2bf(x); a1 = f2bf(x - bf2f(a0));
}
__device__ __forceinline__ void split3(float x, u16& a0, u16& a1, u16& a2) {
    a0 = f2bf(x); float r = x - bf2f(a0);
    a1 = f2bf(r); float r2 = r - bf2f(a1);
    a2 = f2bf(r2);
}
__device__ __forceinline__ uint32 pack2(u16 a, u16 b) { return (uint32)a | ((uint32)b << 16); }
__device__ __forceinline__ uint4 packu4(const u16 (&a)[8]) {
    uint4 v; v.x = pack2(a[0], a[1]); v.y = pack2(a[2], a[3]);
    v.z = pack2(a[4], a[5]); v.w = pack2(a[6], a[7]); return v;
}
__device__ __forceinline__ uint32 comp4(const uint4& v, int c) {
    return c == 0 ? v.x : c == 1 ? v.y : c == 2 ? v.z : v.w;
}
// 8x8 u16 transpose in registers (all indices compile-time under unroll)
__device__ __forceinline__ void transp8(const uint4 (&in)[8], uint4 (&out)[8]) {
#pragma unroll
    for (int c = 0; c < 8; ++c) {
        u16 o[8];
#pragma unroll
        for (int k = 0; k < 8; ++k) o[k] = (u16)(comp4(in[k], c >> 1) >> ((c & 1) * 16));
        out[c].x = pack2(o[0], o[1]); out[c].y = pack2(o[2], o[3]);
        out[c].z = pack2(o[4], o[5]); out[c].w = pack2(o[6], o[7]);
    }
}

// ---------------- 4-wave (256 thr) 2-split 3-pass matmul core ----------------
template<bool PBLDS>
__device__ __forceinline__ void mm2(const uint4* __restrict__ pah, const uint4* __restrict__ pal,
                                    const uint4* __restrict__ pbh, const uint4* __restrict__ pbl,
                                    f32x4 (&acc)[4][4]) {
    const int tid = threadIdx.x, lane = tid & 63, w = tid >> 6;
    const int wr = (w >> 1) * 64, wc = (w & 1) * 64, lr = lane & 15, lg = lane >> 4;
#pragma unroll 1
    for (int kb = 0; kb < 4; ++kb) {
        const int g = kb * 4 + lg;
        bf16x8 ah[4], al[4], bh[4], bl[4];
#pragma unroll
        for (int t = 0; t < 4; ++t) {
            int ra = wr + t * 16 + lr;
            ah[t] = *(const bf16x8*)&pah[g * 128 + ra];
            al[t] = *(const bf16x8*)&pal[g * 128 + ra];
            int rb = wc + t * 16 + lr;
            int ib = PBLDS ? (rb * 16 + (g ^ (rb & 7))) : (g * 128 + rb);
            bh[t] = *(const bf16x8*)&pbh[ib];
            bl[t] = *(const bf16x8*)&pbl[ib];
        }
#pragma unroll
        for (int i = 0; i < 4; ++i)
#pragma unroll
            for (int j = 0; j < 4; ++j) {
                acc[i][j] = MFMA(ah[i], bh[j], acc[i][j], 0, 0, 0);
                acc[i][j] = MFMA(ah[i], bl[j], acc[i][j], 0, 0, 0);
                acc[i][j] = MFMA(al[i], bh[j], acc[i][j], 0, 0, 0);
            }
    }
}

// acc -> LDS pair (swizzled N-form: row w holds result[w][*])
__device__ __forceinline__ void acc_to_lds2(const f32x4 (&acc)[4][4], uint4* Mh, uint4* Ml) {
    const int tid = threadIdx.x, lane = tid & 63, w = tid >> 6;
    const int wr = (w >> 1) * 64, wc = (w & 1) * 64, lr = lane & 15, lg = lane >> 4;
#pragma unroll
    for (int i = 0; i < 4; ++i) {
        int u0 = wr + i * 16 + 4 * lg, half = (u0 >> 2) & 1, gq = u0 >> 3;
#pragma unroll
        for (int j = 0; j < 4; ++j) {
            int m = wc + j * 16 + lr;
            u16 h[4], l[4];
#pragma unroll
            for (int q = 0; q < 4; ++q) split2(acc[i][j][q], h[q], l[q]);
            uint2 hv; hv.x = pack2(h[0], h[1]); hv.y = pack2(h[2], h[3]);
            uint2 lv; lv.x = pack2(l[0], l[1]); lv.y = pack2(l[2], l[3]);
            int base = m * 16 + (gq ^ (m & 7));
            ((uint2*)&Mh[base])[half] = hv;
            ((uint2*)&Ml[base])[half] = lv;
        }
    }
}

// acc -> global FmtG pair (N-form rows)
__device__ __forceinline__ void acc_to_gN(const f32x4 (&acc)[4][4], uint4* nh, uint4* nl) {
    const int tid = threadIdx.x, lane = tid & 63, w = tid >> 6;
    const int wr = (w >> 1) * 64, wc = (w & 1) * 64, lr = lane & 15, lg = lane >> 4;
#pragma unroll
    for (int i = 0; i < 4; ++i) {
        int u0 = wr + i * 16 + 4 * lg, half = (u0 >> 2) & 1, gq = u0 >> 3;
#pragma unroll
        for (int j = 0; j < 4; ++j) {
            int m = wc + j * 16 + lr;
            u16 h[4], l[4];
#pragma unroll
            for (int q = 0; q < 4; ++q) split2(acc[i][j][q], h[q], l[q]);
            uint2 hv; hv.x = pack2(h[0], h[1]); hv.y = pack2(h[2], h[3]);
            uint2 lv; lv.x = pack2(l[0], l[1]); lv.y = pack2(l[2], l[3]);
            int base = gq * 128 + m;
            ((uint2*)&nh[base])[half] = hv;
            ((uint2*)&nl[base])[half] = lv;
        }
    }
}

// acc -> fp32 output (out[w][u])
__device__ __forceinline__ void acc_to_out(const f32x4 (&acc)[4][4], float* O) {
    const int tid = threadIdx.x, lane = tid & 63, w = tid >> 6;
    const int wr = (w >> 1) * 64, wc = (w & 1) * 64, lr = lane & 15, lg = lane >> 4;
#pragma unroll
    for (int i = 0; i < 4; ++i) {
        int u0 = wr + i * 16 + 4 * lg;
#pragma unroll
        for (int j = 0; j < 4; ++j) {
            int m = wc + j * 16 + lr;
            *(f32x4*)&O[m * DIM + u0] = acc[i][j];
        }
    }
}

// ---------------- plane copies ----------------
// global FmtG -> LDS swizzled (content preserved, N-form)
__device__ __forceinline__ void stage_lds(const uint4* sh, const uint4* sl, uint4* Mh, uint4* Ml) {
    for (int s = threadIdx.x; s < GR; s += blockDim.x) {
        int g = s >> 7, row = s & 127;
        int d = row * 16 + (g ^ (row & 7));
        Mh[d] = sh[s]; Ml[d] = sl[s];
    }
}
// LDS pair -> global FmtG pair, straight (N content)
__device__ __forceinline__ void copyN(const uint4* Mh, const uint4* Ml, uint4* dh, uint4* dl) {
    for (int s2 = threadIdx.x; s2 < 2 * GR; s2 += blockDim.x) {
        const uint4* src = (s2 & GR) ? Ml : Mh;
        uint4* dst = (s2 & GR) ? dl : dh;
        int s = s2 & (GR - 1);
        int g = s >> 7, row = s & 127;
        dst[s] = src[row * 16 + (g ^ (row & 7))];
    }
}
// LDS pair -> global FmtG pair, TRANSPOSED (dst[r][c] = src[c][r])
__device__ __forceinline__ void copyT(const uint4* Mh, const uint4* Ml, uint4* dh, uint4* dl) {
    for (int tk = threadIdx.x; tk < 512; tk += blockDim.x) {
        const uint4* src = (tk & 256) ? Ml : Mh;
        uint4* dst = (tk & 256) ? dl : dh;
        int t = tk & 255, br = t >> 4, bc = t & 15;
        uint4 in[8], out[8];
#pragma unroll
        for (int k = 0; k < 8; ++k) { int r = br * 8 + k; in[k] = src[r * 16 + (bc ^ (r & 7))]; }
        transp8(in, out);
#pragma unroll
        for (int k = 0; k < 8; ++k) dst[br * 128 + bc * 8 + k] = out[k];
    }
}

// ============================================================================
// Phase A: fused expm.  2 blocks x 1024 threads (16 waves, wave grid u:4 x w:4,
// 2x2 output tiles per wave).
// B = (P-P^T)/256; PS deg-9 Taylor (B2,B3 + 2 Horner steps); 8 squarings.
// 3-split bf16, 6-pass MFMA everywhere.  X lives in LDS in the 4x16-subtiled
// layout which serves BOTH operands: B-op fragments via contiguous 16B reads,
// A-op (transposed) fragments via scalar u16 column gathers -- no T-form
// materialization, no global round-trip in the squaring loop.
// A-op for MM2..MM4 comes from once-written global FmtG scratch
// (TB = -B = B^T, TB3 = -B3 = B3^T by skewness).
// ============================================================================

// 3-split write of one f32x4 quad (row m, cols u0..u0+3) into subtiled LDS
__device__ __forceinline__ void wlds3s(u16* XSu, int m, int u0, f32x4 v) {
    u16 a0[4], a1[4], a2[4];
#pragma unroll
    for (int q = 0; q < 4; ++q) split3(v[q], a0[q], a1[q], a2[q]);
    int e = ((m >> 2) * 8 + (u0 >> 4)) * 64 + (m & 3) * 16 + (u0 & 15);
    uint2 w0; w0.x = pack2(a0[0], a0[1]); w0.y = pack2(a0[2], a0[3]);
    uint2 w1; w1.x = pack2(a1[0], a1[1]); w1.y = pack2(a1[2], a1[3]);
    uint2 w2; w2.x = pack2(a2[0], a2[1]); w2.y = pack2(a2[2], a2[3]);
    *(uint2*)&XSu[0 * PLANE + e] = w0;
    *(uint2*)&XSu[1 * PLANE + e] = w1;
    *(uint2*)&XSu[2 * PLANE + e] = w2;
}

// column gather: X[8g + j][c] for j=0..7 from subtiled LDS plane.
// e0 = (16g + c/16)*64 + (c&15);  rows j<4 at e0 + j*16, rows j>=4 at +512.
__device__ __forceinline__ bf16x8 col_read(const u16* __restrict__ Xp, int e0) {
    u16 o[8];
#pragma unroll
    for (int j = 0; j < 4; ++j) o[j] = Xp[e0 + j * 16];
#pragma unroll
    for (int j = 0; j < 4; ++j) o[4 + j] = Xp[e0 + 512 + j * 16];
    uint4 v = packu4(o);
    return *(bf16x8*)&v;
}

// 16-wave 3-split 6-pass matmul core.  ATR: A-op via column gathers from
// subtiled LDS (PA = T(X)); else A-op from global FmtG (pa).  B-op always
// subtiled LDS.
template<bool ATR>
__device__ __forceinline__ void mmS(const uint4* __restrict__ pa, const u16* __restrict__ XSu,
                                    f32x4 (&acc)[2][2], int wr, int wc, int lr, int lg) {
#pragma unroll
    for (int i = 0; i < 2; ++i)
#pragma unroll
        for (int j = 0; j < 2; ++j) { f32x4 z = {0.f, 0.f, 0.f, 0.f}; acc[i][j] = z; }
#pragma unroll 1
    for (int kb = 0; kb < 4; ++kb) {
        const int g = kb * 4 + lg;
        bf16x8 aa[2][3], bb[2][3];
        if (ATR) {
#pragma unroll
            for (int t = 0; t < 2; ++t) {
                int e0 = ((16 * g + (wr >> 4) + t) << 6) + lr;
#pragma unroll
                for (int sp = 0; sp < 3; ++sp) aa[t][sp] = col_read(XSu + sp * PLANE, e0);
            }
        } else {
#pragma unroll
            for (int t = 0; t < 2; ++t) {
                int ra = wr + t * 16 + lr;
#pragma unroll
                for (int sp = 0; sp < 3; ++sp) aa[t][sp] = *(const bf16x8*)&pa[sp * GR + g * 128 + ra];
            }
        }
#pragma unroll
        for (int t = 0; t < 2; ++t) {
            int rb = wc + t * 16 + lr;
            int e = ((rb >> 2) * 8 + (g >> 1)) * 64 + (rb & 3) * 16 + (g & 1) * 8;
#pragma unroll
            for (int sp = 0; sp < 3; ++sp) bb[t][sp] = *(const bf16x8*)&XSu[sp * PLANE + e];
        }
#pragma unroll
        for (int i = 0; i < 2; ++i)
#pragma unroll
            for (int j = 0; j < 2; ++j) {
                acc[i][j] = MFMA(aa[i][0], bb[j][0], acc[i][j], 0, 0, 0);
                acc[i][j] = MFMA(aa[i][0], bb[j][1], acc[i][j], 0, 0, 0);
                acc[i][j] = MFMA(aa[i][1], bb[j][0], acc[i][j], 0, 0, 0);
                acc[i][j] = MFMA(aa[i][1], bb[j][1], acc[i][j], 0, 0, 0);
                acc[i][j] = MFMA(aa[i][0], bb[j][2], acc[i][j], 0, 0, 0);
                acc[i][j] = MFMA(aa[i][2], bb[j][0], acc[i][j], 0, 0, 0);
            }
    }
}

__global__ __launch_bounds__(1024) void expm_kernel(
        const float* __restrict__ P, float* __restrict__ NBf, float* __restrict__ NB2f,
        u16* TBp, u16* TB3p,
        u16* TThp, u16* TTlp, u16* TNhp, u16* TNlp) {
    __shared__ uint4 XL[3 * GR];           // 96 KB
    u16* XSu = (u16*)XL;
    const int b = blockIdx.x, tid = threadIdx.x;
    const int lane = tid & 63, w = tid >> 6;
    const int wr = (w >> 2) * 32, wc = (w & 3) * 32, lr = lane & 15, lg = lane >> 4;
    const float* Pm = P + b * MAT;
    float* nbf = NBf + b * MAT;
    float* nb2f = NB2f + b * MAT;
    uint4* tb  = (uint4*)TBp  + (size_t)b * 3 * GR;
    uint4* tb3 = (uint4*)TB3p + (size_t)b * 3 * GR;
    uint4* TTh = (uint4*)TThp; uint4* TTl = (uint4*)TTlp;
    uint4* TNh = (uint4*)TNhp; uint4* TNl = (uint4*)TNlp;

    const float C6f = 1.0f / 720.0f, C7f = 1.0f / 5040.0f, C8f = 1.0f / 40320.0f, C9f = 1.0f / 362880.0f;

    // ---- prep: B = (P - P^T)/256 -> LDS(subtiled) + fp32 NBf + global TB (=-B, FmtG) ----
    for (int s = tid; s < GR; s += 1024) {
        int r = s >> 4, g = s & 15;
        float vv[8];
#pragma unroll
        for (int k = 0; k < 8; ++k) {
            int c = g * 8 + k;
            vv[k] = (Pm[r * DIM + c] - Pm[c * DIM + r]) * (1.0f / 256.0f);
        }
        float4 f0; f0.x = vv[0]; f0.y = vv[1]; f0.z = vv[2]; f0.w = vv[3];
        float4 f1; f1.x = vv[4]; f1.y = vv[5]; f1.z = vv[6]; f1.w = vv[7];
        *(float4*)&nbf[r * DIM + g * 8] = f0;
        *(float4*)&nbf[r * DIM + g * 8 + 4] = f1;
        u16 s0[8], s1[8], s2[8];
#pragma unroll
        for (int k = 0; k < 8; ++k) split3(vv[k], s0[k], s1[k], s2[k]);
        int d = ((r >> 2) * 8 + (g >> 1)) * 64 + (r & 3) * 16 + (g & 1) * 8;
        *(uint4*)&XSu[0 * PLANE + d] = packu4(s0);
        *(uint4*)&XSu[1 * PLANE + d] = packu4(s1);
        *(uint4*)&XSu[2 * PLANE + d] = packu4(s2);
        // negate by sign-flip
#pragma unroll
        for (int k = 0; k < 8; ++k) { s0[k] ^= 0x8000; s1[k] ^= 0x8000; s2[k] ^= 0x8000; }
        int gi = g * 128 + r;
        tb[0 * GR + gi] = packu4(s0); tb[1 * GR + gi] = packu4(s1); tb[2 * GR + gi] = packu4(s2);
    }
    __syncthreads();

    f32x4 acc[2][2];

    // ---- MM1: B2 = B*B  (A = T(B) via column gathers) ----
    mmS<true>(nullptr, XSu, acc, wr, wc, lr, lg);
    __syncthreads();
#pragma unroll
    for (int i = 0; i < 2; ++i) { int u0 = wr + i * 16 + 4 * lg;
#pragma unroll
        for (int j = 0; j < 2; ++j) { int m = wc + j * 16 + lr;
            *(f32x4*)&nb2f[m * DIM + u0] = acc[i][j];
            wlds3s(XSu, m, u0, acc[i][j]);
        } }
    __syncthreads();

    // ---- MM2: B3 = B2*B ; TB3 = -B3 ; X0 -> LDS ----
    mmS<false>(tb, XSu, acc, wr, wc, lr, lg);
    __syncthreads();
#pragma unroll
    for (int i = 0; i < 2; ++i) { int u0 = wr + i * 16 + 4 * lg; int half = (u0 >> 2) & 1; int gi = (u0 >> 3) * 128;
#pragma unroll
        for (int j = 0; j < 2; ++j) { int m = wc + j * 16 + lr;
            f32x4 a = acc[i][j];
            u16 a0[4], a1[4], a2[4];
#pragma unroll
            for (int q = 0; q < 4; ++q) split3(-a[q], a0[q], a1[q], a2[q]);
            uint2 w0; w0.x = pack2(a0[0], a0[1]); w0.y = pack2(a0[2], a0[3]);
            uint2 w1; w1.x = pack2(a1[0], a1[1]); w1.y = pack2(a1[2], a1[3]);
            uint2 w2; w2.x = pack2(a2[0], a2[1]); w2.y = pack2(a2[2], a2[3]);
            ((uint2*)&tb3[0 * GR + gi + m])[half] = w0;
            ((uint2*)&tb3[1 * GR + gi + m])[half] = w1;
            ((uint2*)&tb3[2 * GR + gi + m])[half] = w2;
            f32x4 bv = *(const f32x4*)&nbf[m * DIM + u0];
            f32x4 b2v = *(const f32x4*)&nb2f[m * DIM + u0];
            f32x4 x0;
#pragma unroll
            for (int q = 0; q < 4; ++q)
                x0[q] = a[q] * C9f + b2v[q] * C8f + bv[q] * C7f + ((u0 + q == m) ? C6f : 0.0f);
            wlds3s(XSu, m, u0, x0);
        } }
    __syncthreads();

    // ---- MM3: X1 = X0*B3 + (I/6 + B/24 + B2/120) ----
    mmS<false>(tb3, XSu, acc, wr, wc, lr, lg);
    __syncthreads();
#pragma unroll
    for (int i = 0; i < 2; ++i) { int u0 = wr + i * 16 + 4 * lg;
#pragma unroll
        for (int j = 0; j < 2; ++j) { int m = wc + j * 16 + lr;
            f32x4 bv = *(const f32x4*)&nbf[m * DIM + u0];
            f32x4 b2v = *(const f32x4*)&nb2f[m * DIM + u0];
            f32x4 x1;
#pragma unroll
            for (int q = 0; q < 4; ++q)
                x1[q] = acc[i][j][q] + bv[q] * (1.0f / 24.0f) + b2v[q] * (1.0f / 120.0f)
                      + ((u0 + q == m) ? (1.0f / 6.0f) : 0.0f);
            wlds3s(XSu, m, u0, x1);
        } }
    __syncthreads();

    // ---- MM4: X2 = X1*B3 + (I + B + B2/2) ----
    mmS<false>(tb3, XSu, acc, wr, wc, lr, lg);
    __syncthreads();
#pragma unroll
    for (int i = 0; i < 2; ++i) { int u0 = wr + i * 16 + 4 * lg;
#pragma unroll
        for (int j = 0; j < 2; ++j) { int m = wc + j * 16 + lr;
            f32x4 bv = *(const f32x4*)&nbf[m * DIM + u0];
            f32x4 b2v = *(const f32x4*)&nb2f[m * DIM + u0];
            f32x4 x2;
#pragma unroll
            for (int q = 0; q < 4; ++q)
                x2[q] = acc[i][j][q] + bv[q] + b2v[q] * 0.5f + ((u0 + q == m) ? 1.0f : 0.0f);
            wlds3s(XSu, m, u0, x2);
        } }
    __syncthreads();

    // ---- 8 squarings, entirely in LDS ----
    for (int sq = 0; sq < 8; ++sq) {
        mmS<true>(nullptr, XSu, acc, wr, wc, lr, lg);
        __syncthreads();
        if (sq < 7) {
#pragma unroll
            for (int i = 0; i < 2; ++i) { int u0 = wr + i * 16 + 4 * lg;
#pragma unroll
                for (int j = 0; j < 2; ++j) wlds3s(XSu, wc + j * 16 + lr, u0, acc[i][j]);
            }
            __syncthreads();
        } else {
            // acc = exp(herm).  T_b = exp^T:  TT[b] = T(T_b) = exp (straight);
            // TN[b] = N(T_b) = exp^T (transposed).  2-split via standard-layout
            // LDS planes 0,1, then existing copyN/copyT.
#pragma unroll
            for (int i = 0; i < 2; ++i) { int u0 = wr + i * 16 + 4 * lg; int half = (u0 >> 2) & 1;
#pragma unroll
                for (int j = 0; j < 2; ++j) { int m = wc + j * 16 + lr;
                    u16 h[4], l[4];
#pragma unroll
                    for (int q = 0; q < 4; ++q) split2(acc[i][j][q], h[q], l[q]);
                    uint2 hv; hv.x = pack2(h[0], h[1]); hv.y = pack2(h[2], h[3]);
                    uint2 lv; lv.x = pack2(l[0], l[1]); lv.y = pack2(l[2], l[3]);
                    int base = m * 16 + ((u0 >> 3) ^ (m & 7));
                    ((uint2*)&XL[0 * GR + base])[half] = hv;
                    ((uint2*)&XL[1 * GR + base])[half] = lv;
                } }
            __syncthreads();
            copyN(XL, XL + GR, TTh + (size_t)b * GR, TTl + (size_t)b * GR);
            copyT(XL, XL + GR, TNh + (size_t)b * GR, TNl + (size_t)b * GR);
        }
    }
}

// ============================================================================
// Phase B1: chains for v in [4,32) (+ identity plane).  29 blocks x 256 thr.
// V(v) = T_{b0} * T_{b1} * ... (bits LSB-first, leading 1 dropped).
// ============================================================================
__global__ __launch_bounds__(256) void chain_kernel(u16* TThp, u16* TTlp, u16* TNhp, u16* TNlp,
                                                    int schemeA) {
    __shared__ uint4 Mh[GR], Ml[GR];
    uint4* TTh = (uint4*)TThp; uint4* TTl = (uint4*)TTlp;
    uint4* TNh = (uint4*)TNhp; uint4* TNl = (uint4*)TNlp;
    int b = blockIdx.x;
    if (b == 28) {                           // identity N-plane
        int id = schemeA ? 274 : 126;
        for (int s = threadIdx.x; s < GR; s += 256) {
            int g = s >> 7, row = s & 127;
            u16 h[8];
#pragma unroll
            for (int k = 0; k < 8; ++k) h[k] = (g * 8 + k == row) ? (u16)0x3F80 : (u16)0;
            TNh[(size_t)id * GR + s] = packu4(h);
            uint4 z; z.x = z.y = z.z = z.w = 0u;
            TNl[(size_t)id * GR + s] = z;
        }
        return;
    }
    int v = 4 + b;
    int nb = 31 - __clz(v);                  // path length
    int b0 = v & 1;
    stage_lds(TNh + (size_t)b0 * GR, TNl + (size_t)b0 * GR, Mh, Ml);
    __syncthreads();
    for (int t = 1; t < nb; ++t) {
        int bt = (v >> t) & 1;
        f32x4 acc[4][4] = {};
        mm2<true>(TTh + (size_t)bt * GR, TTl + (size_t)bt * GR, Mh, Ml, acc);
        __syncthreads();
        acc_to_lds2(acc, Mh, Ml);
        __syncthreads();
    }
    copyT(Mh, Ml, TTh + (size_t)(v - 2) * GR, TTl + (size_t)(v - 2) * GR);
    bool needN = schemeA ? (v >= 16) : true;
    if (needN) {
        int tn = schemeA ? (v - 14) : (v - 2);
        copyN(Mh, Ml, TNh + (size_t)tn * GR, TNl + (size_t)tn * GR);
    }
}

// ============================================================================
// Phase B2: all remaining v in one launch: V(v) = C4(v&15) * V(v>>4).
// schemeA: v in [32,512), 480 blocks.  schemeB: v in [32,128), 96 blocks.
// ============================================================================
__global__ __launch_bounds__(256) void pair_kernel(u16* TThp, u16* TTlp, u16* TNhp, u16* TNlp,
                                                   int schemeA) {
    __shared__ uint4 Mh[GR], Ml[GR];
    uint4* TTh = (uint4*)TThp; uint4* TTl = (uint4*)TTlp;
    uint4* TNh = (uint4*)TNhp; uint4* TNl = (uint4*)TNlp;
    int v = 32 + blockIdx.x;
    int c4 = v & 15;
    int tnb = schemeA ? (2 + c4) : (14 + c4);          // slot of N(V(16+c4))
    int tta = (v >> 4) - 2;                            // slot of T(V(v>>4))
    f32x4 acc[4][4] = {};
    mm2<false>(TTh + (size_t)tta * GR, TTl + (size_t)tta * GR,
               TNh + (size_t)tnb * GR, TNl + (size_t)tnb * GR, acc);
    bool wN = schemeA ? (v >= 256) : true;
    bool wT = schemeA ? (v < 256) : true;
    if (wN) {
        int tn = schemeA ? (18 + (v - 256)) : (v - 2);
        acc_to_gN(acc, TNh + (size_t)tn * GR, TNl + (size_t)tn * GR);
    }
    if (wT) {
        acc_to_lds2(acc, Mh, Ml);
        __syncthreads();
        copyT(Mh, Ml, TTh + (size_t)(v - 2) * GR, TTl + (size_t)(v - 2) * GR);
    }
}

// ============================================================================
// Phase C: one block per position.
// schemeA: maps(p) = C8(p&255) * V(p>>8) -> ONE matmul, operands from global,
//          zero LDS.  schemeB: 6-bit chunks, <=2 matmuls, 64 KB dynamic LDS.
// ============================================================================
__global__ __launch_bounds__(256) void final_kernel(const u16* TThp, const u16* TTlp,
                                                    const u16* TNhp, const u16* TNlp,
                                                    const int* __restrict__ uq,
                                                    float* __restrict__ out, int schemeA) {
    extern __shared__ uint4 FL[];
    const uint4* TTh = (const uint4*)TThp; const uint4* TTl = (const uint4*)TTlp;
    const uint4* TNh = (const uint4*)TNhp; const uint4* TNl = (const uint4*)TNlp;
    float* O = out + (size_t)blockIdx.x * MAT;
    unsigned p = (unsigned)uq[blockIdx.x];

    if (p < 2u) {                                      // identity output
        for (int s = threadIdx.x; s < 4096; s += 256) {
            int r = s >> 5, c0 = (s & 31) * 4;
            float4 v; v.x = v.y = v.z = v.w = 0.f;
            int d = r - c0;
            if (d == 0) v.x = 1.f; else if (d == 1) v.y = 1.f;
            else if (d == 2) v.z = 1.f; else if (d == 3) v.w = 1.f;
            *(float4*)&O[r * DIM + c0] = v;
        }
        return;
    }

    const uint4 *pah, *pal, *pbh, *pbl;
    int m3 = -1;
    if (schemeA) {
        const int id = 274;
        if (p < 256u) {                                // out = V(p) * I
            pah = TTh + (size_t)(p - 2) * GR; pal = TTl + (size_t)(p - 2) * GR;
            pbh = TNh + (size_t)id * GR;      pbl = TNl + (size_t)id * GR;
        } else {
            int lo = (int)(p & 255u); unsigned hi = p >> 8;
            pbh = TNh + (size_t)(18 + lo) * GR; pbl = TNl + (size_t)(18 + lo) * GR;
            if (hi >= 2u) { pah = TTh + (size_t)(hi - 2) * GR; pal = TTl + (size_t)(hi - 2) * GR; }
            else          { pah = TNh + (size_t)id * GR;       pal = TNl + (size_t)id * GR; }
        }
    } else {
        int f[3]; int m = 0; unsigned q = p;
        while (q >= 128u) { f[m++] = 64 + (int)(q & 63u); q >>= 6; }
        f[m++] = (int)q;
        if (m == 1) {                                  // out = V(p) directly
            const uint4* sh = TNh + (size_t)(f[0] - 2) * GR;
            const uint4* sl = TNl + (size_t)(f[0] - 2) * GR;
            for (int s = threadIdx.x; s < GR; s += 256) {
                int row = s >> 4, g = s & 15;
                uint4 H = sh[g * 128 + row], L = sl[g * 128 + row];
                float4 o0, o1;
                o0.x = bf2f((u16)(H.x & 0xffff)) + bf2f((u16)(L.x & 0xffff));
                o0.y = bf2f((u16)(H.x >> 16))    + bf2f((u16)(L.x >> 16));
                o0.z = bf2f((u16)(H.y & 0xffff)) + bf2f((u16)(L.y & 0xffff));
                o0.w = bf2f((u16)(H.y >> 16))    + bf2f((u16)(L.y >> 16));
                o1.x = bf2f((u16)(H.z & 0xffff)) + bf2f((u16)(L.z & 0xffff));
                o1.y = bf2f((u16)(H.z >> 16))    + bf2f((u16)(L.z >> 16));
                o1.z = bf2f((u16)(H.w & 0xffff)) + bf2f((u16)(L.w & 0xffff));
                o1.w = bf2f((u16)(H.w >> 16))    + bf2f((u16)(L.w >> 16));
                *(float4*)&O[row * DIM + g * 8] = o0;
                *(float4*)&O[row * DIM + g * 8 + 4] = o1;
            }
            return;
        }
        pbh = TNh + (size_t)(f[0] - 2) * GR; pbl = TNl + (size_t)(f[0] - 2) * GR;
        pah = TTh + (size_t)(f[1] - 2) * GR; pal = TTl + (size_t)(f[1] - 2) * GR;
        if (m == 3) m3 = f[2] - 2;
    }

    f32x4 acc[4][4] = {};
    mm2<false>(pah, pal, pbh, pbl, acc);
    if (m3 < 0) { acc_to_out(acc, O); return; }
    acc_to_lds2(acc, FL, FL + GR);
    __syncthreads();
    f32x4 a2[4][4] = {};
    mm2<true>(TTh + (size_t)m3 * GR, TTl + (size_t)m3 * GR, FL, FL + GR, a2);
    acc_to_out(a2, O);
}

// ============================================================================
// launch
// ============================================================================
extern "C" void kernel_launch(void* const* d_in, const int* in_sizes, int n_in,
                              void* d_out, int out_size, void* d_ws, size_t ws_size,
                              hipStream_t stream) {
    const int*   uq = (const int*)d_in[0];
    const float* P  = (const float*)d_in[1];
    float* out = (float*)d_out;

    // scheme A (8/8 split, 1-matmul final) needs ~33.9 MiB; else 6-bit scheme (~16.6 MiB)
    const size_t needA = (size_t)(2 * 254 + 2 * 275 + 18) * MAT * 2 + (size_t)4 * MAT * 4;
    const bool A = ws_size >= needA;
    const int nTT = A ? 254 : 126;
    const int nTN = A ? 275 : 127;

    u16* TTh = (u16*)d_ws;
    u16* TTl = TTh + (size_t)nTT * MAT;
    u16* TNh = TTl + (size_t)nTT * MAT;
    u16* TNl = TNh + (size_t)nTN * MAT;
    u16* TB  = TNl + (size_t)nTN * MAT;     // [2][3][MAT]
    u16* TB3 = TB  + (size_t)6 * MAT;
    u16* XTg = TB3 + (size_t)6 * MAT;       // (retired scratch, kept for layout stability)
    float* NBf  = (float*)(XTg + (size_t)6 * MAT);
    float* NB2f = NBf + 2 * MAT;

    expm_kernel<<<2, 1024, 0, stream>>>(P, NBf, NB2f, TB, TB3, TTh, TTl, TNh, TNl);
    chain_kernel<<<29, 256, 0, stream>>>(TTh, TTl, TNh, TNl, (int)A);
    pair_kernel<<<A ? 480 : 96, 256, 0, stream>>>(TTh, TTl, TNh, TNl, (int)A);
    final_kernel<<<1024, 256, A ? 0 : 65536, stream>>>(TTh, TTl, TNh, TNl, uq, out, (int)A);
}

// Round 3
// 157.149 us; speedup vs baseline: 1.1997x; 1.1904x over previous
//
#include <hip/hip_runtime.h>

typedef unsigned int uint32;
typedef unsigned short u16;
typedef __attribute__((ext_vector_type(8))) short bf16x8;
typedef __attribute__((ext_vector_type(4))) float f32x4;
typedef __attribute__((ext_vector_type(2))) uint32 u32x2;
typedef __attribute__((ext_vector_type(4))) uint32 u32x4;

#define DIM 128
#define MAT (DIM * DIM)
#define GR  2048                 // uint4 granules per 128x128 bf16 plane (32 KB)
#define PLANE 16384              // u16 elements per plane
#define MFMA __builtin_amdgcn_mfma_f32_16x16x32_bf16

// Plane formats:
//  FmtG (global bf16 planes): uint4 granule index = g*128 + row   (g = col/8)
//  LDS standard (chain/pair/final + expm final staging): uint4 idx = row*16 + (g ^ (row&7))
//  LDS subtiled (expm internal, serves BOTH mfma operands):
//    element (r,c) at  ((r>>2)*8 + (c>>4))*64 + (r&3)*16 + (c&15)
//    - row fragment (fixed r, 8 consecutive c): contiguous 16 B  -> ds_read_b128
//    - col fragment (fixed c, consecutive r):   ds_read_b64_tr_b16.
//      tr_b16 semantics (m162-derived): result = column (addr>>3)&15 of the
//      4x16 row-major bf16 tile at (addr & ~127); so pass addr =
//      subtile_base_bytes + 8*col_in_subtile.  (Round-0 bug: used +2*col.)
// Core semantic (verified rounds 2/3): with a-frags from PA rows u and b-frags
// from PB rows w,  D[u][w] = sum_k PA[u][k]*PB[w][k]; the f32x4 acc spans 4
// consecutive u at fixed w.  For out = L*R: PA = T(R), PB = N(L), out[w][u]=D.

// ---------------- scalar helpers ----------------
__device__ __forceinline__ u16 f2bf(float x) {
    uint32 u = __float_as_uint(x);
    u += 0x7fffu + ((u >> 16) & 1u);
    return (u16)(u >> 16);
}
__device__ __forceinline__ float bf2f(u16 h) { return __uint_as_float(((uint32)h) << 16); }
__device__ __forceinline__ void split2(float x, u16& a0, u16& a1) {
    a0 = f2bf(x); a1 = f2bf(x - bf2f(a0));
}
__device__ __forceinline__ void split3(float x, u16& a0, u16& a1, u16& a2) {
    a0 = f2bf(x); float r = x - bf2f(a0);
    a1 = f2bf(r); float r2 = r - bf2f(a1);
    a2 = f2bf(r2);
}
__device__ __forceinline__ uint32 pack2(u16 a, u16 b) { return (uint32)a | ((uint32)b << 16); }
__device__ __forceinline__ uint4 packu4(const u16 (&a)[8]) {
    uint4 v; v.x = pack2(a[0], a[1]); v.y = pack2(a[2], a[3]);
    v.z = pack2(a[4], a[5]); v.w = pack2(a[6], a[7]); return v;
}
__device__ __forceinline__ uint32 comp4(const uint4& v, int c) {
    return c == 0 ? v.x : c == 1 ? v.y : c == 2 ? v.z : v.w;
}
// 8x8 u16 transpose in registers (all indices compile-time under unroll)
__device__ __forceinline__ void transp8(const uint4 (&in)[8], uint4 (&out)[8]) {
#pragma unroll
    for (int c = 0; c < 8; ++c) {
        u16 o[8];
#pragma unroll
        for (int k = 0; k < 8; ++k) o[k] = (u16)(comp4(in[k], c >> 1) >> ((c & 1) * 16));
        out[c].x = pack2(o[0], o[1]); out[c].y = pack2(o[2], o[3]);
        out[c].z = pack2(o[4], o[5]); out[c].w = pack2(o[6], o[7]);
    }
}

// ---------------- 4-wave (256 thr) 2-split 3-pass matmul core ----------------
template<bool PBLDS>
__device__ __forceinline__ void mm2(const uint4* __restrict__ pah, const uint4* __restrict__ pal,
                                    const uint4* __restrict__ pbh, const uint4* __restrict__ pbl,
                                    f32x4 (&acc)[4][4]) {
    const int tid = threadIdx.x, lane = tid & 63, w = tid >> 6;
    const int wr = (w >> 1) * 64, wc = (w & 1) * 64, lr = lane & 15, lg = lane >> 4;
#pragma unroll 1
    for (int kb = 0; kb < 4; ++kb) {
        const int g = kb * 4 + lg;
        bf16x8 ah[4], al[4], bh[4], bl[4];
#pragma unroll
        for (int t = 0; t < 4; ++t) {
            int ra = wr + t * 16 + lr;
            ah[t] = *(const bf16x8*)&pah[g * 128 + ra];
            al[t] = *(const bf16x8*)&pal[g * 128 + ra];
            int rb = wc + t * 16 + lr;
            int ib = PBLDS ? (rb * 16 + (g ^ (rb & 7))) : (g * 128 + rb);
            bh[t] = *(const bf16x8*)&pbh[ib];
            bl[t] = *(const bf16x8*)&pbl[ib];
        }
#pragma unroll
        for (int i = 0; i < 4; ++i)
#pragma unroll
            for (int j = 0; j < 4; ++j) {
                acc[i][j] = MFMA(ah[i], bh[j], acc[i][j], 0, 0, 0);
                acc[i][j] = MFMA(ah[i], bl[j], acc[i][j], 0, 0, 0);
                acc[i][j] = MFMA(al[i], bh[j], acc[i][j], 0, 0, 0);
            }
    }
}

// acc -> LDS pair (swizzled N-form: row w holds result[w][*])
__device__ __forceinline__ void acc_to_lds2(const f32x4 (&acc)[4][4], uint4* Mh, uint4* Ml) {
    const int tid = threadIdx.x, lane = tid & 63, w = tid >> 6;
    const int wr = (w >> 1) * 64, wc = (w & 1) * 64, lr = lane & 15, lg = lane >> 4;
#pragma unroll
    for (int i = 0; i < 4; ++i) {
        int u0 = wr + i * 16 + 4 * lg, half = (u0 >> 2) & 1, gq = u0 >> 3;
#pragma unroll
        for (int j = 0; j < 4; ++j) {
            int m = wc + j * 16 + lr;
            u16 h[4], l[4];
#pragma unroll
            for (int q = 0; q < 4; ++q) split2(acc[i][j][q], h[q], l[q]);
            uint2 hv; hv.x = pack2(h[0], h[1]); hv.y = pack2(h[2], h[3]);
            uint2 lv; lv.x = pack2(l[0], l[1]); lv.y = pack2(l[2], l[3]);
            int base = m * 16 + (gq ^ (m & 7));
            ((uint2*)&Mh[base])[half] = hv;
            ((uint2*)&Ml[base])[half] = lv;
        }
    }
}

// acc -> global FmtG pair (N-form rows)
__device__ __forceinline__ void acc_to_gN(const f32x4 (&acc)[4][4], uint4* nh, uint4* nl) {
    const int tid = threadIdx.x, lane = tid & 63, w = tid >> 6;
    const int wr = (w >> 1) * 64, wc = (w & 1) * 64, lr = lane & 15, lg = lane >> 4;
#pragma unroll
    for (int i = 0; i < 4; ++i) {
        int u0 = wr + i * 16 + 4 * lg, half = (u0 >> 2) & 1, gq = u0 >> 3;
#pragma unroll
        for (int j = 0; j < 4; ++j) {
            int m = wc + j * 16 + lr;
            u16 h[4], l[4];
#pragma unroll
            for (int q = 0; q < 4; ++q) split2(acc[i][j][q], h[q], l[q]);
            uint2 hv; hv.x = pack2(h[0], h[1]); hv.y = pack2(h[2], h[3]);
            uint2 lv; lv.x = pack2(l[0], l[1]); lv.y = pack2(l[2], l[3]);
            int base = gq * 128 + m;
            ((uint2*)&nh[base])[half] = hv;
            ((uint2*)&nl[base])[half] = lv;
        }
    }
}

// acc -> fp32 output (out[w][u])
__device__ __forceinline__ void acc_to_out(const f32x4 (&acc)[4][4], float* O) {
    const int tid = threadIdx.x, lane = tid & 63, w = tid >> 6;
    const int wr = (w >> 1) * 64, wc = (w & 1) * 64, lr = lane & 15, lg = lane >> 4;
#pragma unroll
    for (int i = 0; i < 4; ++i) {
        int u0 = wr + i * 16 + 4 * lg;
#pragma unroll
        for (int j = 0; j < 4; ++j) {
            int m = wc + j * 16 + lr;
            *(f32x4*)&O[m * DIM + u0] = acc[i][j];
        }
    }
}

// ---------------- plane copies ----------------
// global FmtG -> LDS swizzled (content preserved, N-form)
__device__ __forceinline__ void stage_lds(const uint4* sh, const uint4* sl, uint4* Mh, uint4* Ml) {
    for (int s = threadIdx.x; s < GR; s += blockDim.x) {
        int g = s >> 7, row = s & 127;
        int d = row * 16 + (g ^ (row & 7));
        Mh[d] = sh[s]; Ml[d] = sl[s];
    }
}
// LDS pair -> global FmtG pair, straight (N content)
__device__ __forceinline__ void copyN(const uint4* Mh, const uint4* Ml, uint4* dh, uint4* dl) {
    for (int s2 = threadIdx.x; s2 < 2 * GR; s2 += blockDim.x) {
        const uint4* src = (s2 & GR) ? Ml : Mh;
        uint4* dst = (s2 & GR) ? dl : dh;
        int s = s2 & (GR - 1);
        int g = s >> 7, row = s & 127;
        dst[s] = src[row * 16 + (g ^ (row & 7))];
    }
}
// LDS pair -> global FmtG pair, TRANSPOSED (dst[r][c] = src[c][r])
__device__ __forceinline__ void copyT(const uint4* Mh, const uint4* Ml, uint4* dh, uint4* dl) {
    for (int tk = threadIdx.x; tk < 512; tk += blockDim.x) {
        const uint4* src = (tk & 256) ? Ml : Mh;
        uint4* dst = (tk & 256) ? dl : dh;
        int t = tk & 255, br = t >> 4, bc = t & 15;
        uint4 in[8], out[8];
#pragma unroll
        for (int k = 0; k < 8; ++k) { int r = br * 8 + k; in[k] = src[r * 16 + (bc ^ (r & 7))]; }
        transp8(in, out);
#pragma unroll
        for (int k = 0; k < 8; ++k) dst[br * 128 + bc * 8 + k] = out[k];
    }
}

// ============================================================================
// Phase A: fused expm.  2 blocks x 1024 threads (16 waves, wave grid u:4 x w:4,
// 2x2 output tiles per wave).
// B = (P-P^T)/256; PS deg-9 Taylor (B2,B3 + 2 Horner steps); 8 squarings.
// 3-split bf16, 6-pass MFMA everywhere.  X lives in LDS in the 4x16-subtiled
// layout which serves BOTH operands: B-op fragments via contiguous ds_read_b128,
// A-op (transposed) fragments via hardware ds_read_b64_tr_b16 -- no T-form
// materialization, no global round-trip in the squaring loop.
// A-op for MM2..MM4 comes from once-written global FmtG scratch
// (TB = -B = B^T, TB3 = -B3 = B3^T by skewness).
// ============================================================================

// 3-split write of one f32x4 quad (row m, cols u0..u0+3) into subtiled LDS
__device__ __forceinline__ void wlds3s(u16* XSu, int m, int u0, f32x4 v) {
    u16 a0[4], a1[4], a2[4];
#pragma unroll
    for (int q = 0; q < 4; ++q) split3(v[q], a0[q], a1[q], a2[q]);
    int e = ((m >> 2) * 8 + (u0 >> 4)) * 64 + (m & 3) * 16 + (u0 & 15);
    uint2 w0; w0.x = pack2(a0[0], a0[1]); w0.y = pack2(a0[2], a0[3]);
    uint2 w1; w1.x = pack2(a1[0], a1[1]); w1.y = pack2(a1[2], a1[3]);
    uint2 w2; w2.x = pack2(a2[0], a2[1]); w2.y = pack2(a2[2], a2[3]);
    *(uint2*)&XSu[0 * PLANE + e] = w0;
    *(uint2*)&XSu[1 * PLANE + e] = w1;
    *(uint2*)&XSu[2 * PLANE + e] = w2;
}

// 16-wave 3-split 6-pass matmul core.  ATR: A-op via ds_read_b64_tr_b16 from
// subtiled LDS (PA = T(X)); else A-op from global FmtG (pa).  B-op always
// subtiled LDS.
template<bool ATR>
__device__ __forceinline__ void mmS(const uint4* __restrict__ pa, const u16* __restrict__ XSu,
                                    f32x4 (&acc)[2][2], int wr, int wc, int lr, int lg) {
#pragma unroll
    for (int i = 0; i < 2; ++i)
#pragma unroll
        for (int j = 0; j < 2; ++j) { f32x4 z = {0.f, 0.f, 0.f, 0.f}; acc[i][j] = z; }
    const uint32 lds_base = (uint32)(size_t)(const void*)XSu;
#pragma unroll 1
    for (int kb = 0; kb < 4; ++kb) {
        const int g = kb * 4 + lg;
        u32x2 t0[2][3], t1[2][3];
        bf16x8 aa[2][3], bb[2][3];
        if (ATR) {
            // column ra = wr + t*16 + lr of X, rows 8g..8g+7.
            // tile = subtile (16g + wr/16 + t) at byte (16g + wr/16 + t)*128;
            // column select = (addr>>3)&15 = lr  ->  addr = tile_base + 8*lr.
            // rows 4..7 live one subtile-row (8 subtiles = 1024 B) ahead.
#pragma unroll
            for (int t = 0; t < 2; ++t) {
                uint32 ba = lds_base + (uint32)(((16 * g + (wr >> 4) + t) << 7) + 8 * lr);
#pragma unroll
                for (int sp = 0; sp < 3; ++sp) {
                    asm volatile("ds_read_b64_tr_b16 %0, %2\n\t"
                                 "ds_read_b64_tr_b16 %1, %2 offset:1024"
                                 : "=&v"(t0[t][sp]), "=&v"(t1[t][sp])
                                 : "v"(ba + (uint32)(sp * 2 * PLANE)));
                }
            }
        } else {
#pragma unroll
            for (int t = 0; t < 2; ++t) {
                int ra = wr + t * 16 + lr;
#pragma unroll
                for (int sp = 0; sp < 3; ++sp) aa[t][sp] = *(const bf16x8*)&pa[sp * GR + g * 128 + ra];
            }
        }
#pragma unroll
        for (int t = 0; t < 2; ++t) {
            int rb = wc + t * 16 + lr;
            int e = ((rb >> 2) * 8 + (g >> 1)) * 64 + (rb & 3) * 16 + (g & 1) * 8;
#pragma unroll
            for (int sp = 0; sp < 3; ++sp) bb[t][sp] = *(const bf16x8*)&XSu[sp * PLANE + e];
        }
        if (ATR) {
            // rule #18: drain asm ds_reads, then fence scheduling so the fragment
            // assembly + MFMAs cannot be hoisted above the wait.
            asm volatile("s_waitcnt lgkmcnt(0)" ::: "memory");
            __builtin_amdgcn_sched_barrier(0);
#pragma unroll
            for (int t = 0; t < 2; ++t)
#pragma unroll
                for (int sp = 0; sp < 3; ++sp) {
                    u32x4 v; v.x = t0[t][sp].x; v.y = t0[t][sp].y;
                    v.z = t1[t][sp].x; v.w = t1[t][sp].y;
                    aa[t][sp] = *(bf16x8*)&v;
                }
        }
#pragma unroll
        for (int i = 0; i < 2; ++i)
#pragma unroll
            for (int j = 0; j < 2; ++j) {
                acc[i][j] = MFMA(aa[i][0], bb[j][0], acc[i][j], 0, 0, 0);
                acc[i][j] = MFMA(aa[i][0], bb[j][1], acc[i][j], 0, 0, 0);
                acc[i][j] = MFMA(aa[i][1], bb[j][0], acc[i][j], 0, 0, 0);
                acc[i][j] = MFMA(aa[i][1], bb[j][1], acc[i][j], 0, 0, 0);
                acc[i][j] = MFMA(aa[i][0], bb[j][2], acc[i][j], 0, 0, 0);
                acc[i][j] = MFMA(aa[i][2], bb[j][0], acc[i][j], 0, 0, 0);
            }
    }
}

__global__ __launch_bounds__(1024) void expm_kernel(
        const float* __restrict__ P, float* __restrict__ NBf, float* __restrict__ NB2f,
        u16* TBp, u16* TB3p,
        u16* TThp, u16* TTlp, u16* TNhp, u16* TNlp) {
    __shared__ uint4 XL[3 * GR];           // 96 KB
    u16* XSu = (u16*)XL;
    const int b = blockIdx.x, tid = threadIdx.x;
    const int lane = tid & 63, w = tid >> 6;
    const int wr = (w >> 2) * 32, wc = (w & 3) * 32, lr = lane & 15, lg = lane >> 4;
    const float* Pm = P + b * MAT;
    float* nbf = NBf + b * MAT;
    float* nb2f = NB2f + b * MAT;
    uint4* tb  = (uint4*)TBp  + (size_t)b * 3 * GR;
    uint4* tb3 = (uint4*)TB3p + (size_t)b * 3 * GR;
    uint4* TTh = (uint4*)TThp; uint4* TTl = (uint4*)TTlp;
    uint4* TNh = (uint4*)TNhp; uint4* TNl = (uint4*)TNlp;

    const float C6f = 1.0f / 720.0f, C7f = 1.0f / 5040.0f, C8f = 1.0f / 40320.0f, C9f = 1.0f / 362880.0f;

    // ---- prep: B = (P - P^T)/256 -> LDS(subtiled) + fp32 NBf + global TB (=-B, FmtG) ----
    for (int s = tid; s < GR; s += 1024) {
        int r = s >> 4, g = s & 15;
        float vv[8];
#pragma unroll
        for (int k = 0; k < 8; ++k) {
            int c = g * 8 + k;
            vv[k] = (Pm[r * DIM + c] - Pm[c * DIM + r]) * (1.0f / 256.0f);
        }
        float4 f0; f0.x = vv[0]; f0.y = vv[1]; f0.z = vv[2]; f0.w = vv[3];
        float4 f1; f1.x = vv[4]; f1.y = vv[5]; f1.z = vv[6]; f1.w = vv[7];
        *(float4*)&nbf[r * DIM + g * 8] = f0;
        *(float4*)&nbf[r * DIM + g * 8 + 4] = f1;
        u16 s0[8], s1[8], s2[8];
#pragma unroll
        for (int k = 0; k < 8; ++k) split3(vv[k], s0[k], s1[k], s2[k]);
        int d = ((r >> 2) * 8 + (g >> 1)) * 64 + (r & 3) * 16 + (g & 1) * 8;
        *(uint4*)&XSu[0 * PLANE + d] = packu4(s0);
        *(uint4*)&XSu[1 * PLANE + d] = packu4(s1);
        *(uint4*)&XSu[2 * PLANE + d] = packu4(s2);
        // negate by sign-flip
#pragma unroll
        for (int k = 0; k < 8; ++k) { s0[k] ^= 0x8000; s1[k] ^= 0x8000; s2[k] ^= 0x8000; }
        int gi = g * 128 + r;
        tb[0 * GR + gi] = packu4(s0); tb[1 * GR + gi] = packu4(s1); tb[2 * GR + gi] = packu4(s2);
    }
    __syncthreads();

    f32x4 acc[2][2];

    // ---- MM1: B2 = B*B  (A = T(B) via tr-reads) ----
    mmS<true>(nullptr, XSu, acc, wr, wc, lr, lg);
    __syncthreads();
#pragma unroll
    for (int i = 0; i < 2; ++i) { int u0 = wr + i * 16 + 4 * lg;
#pragma unroll
        for (int j = 0; j < 2; ++j) { int m = wc + j * 16 + lr;
            *(f32x4*)&nb2f[m * DIM + u0] = acc[i][j];
            wlds3s(XSu, m, u0, acc[i][j]);
        } }
    __syncthreads();

    // ---- MM2: B3 = B2*B ; TB3 = -B3 ; X0 -> LDS ----
    mmS<false>(tb, XSu, acc, wr, wc, lr, lg);
    __syncthreads();
#pragma unroll
    for (int i = 0; i < 2; ++i) { int u0 = wr + i * 16 + 4 * lg; int half = (u0 >> 2) & 1; int gi = (u0 >> 3) * 128;
#pragma unroll
        for (int j = 0; j < 2; ++j) { int m = wc + j * 16 + lr;
            f32x4 a = acc[i][j];
            u16 a0[4], a1[4], a2[4];
#pragma unroll
            for (int q = 0; q < 4; ++q) split3(-a[q], a0[q], a1[q], a2[q]);
            uint2 w0; w0.x = pack2(a0[0], a0[1]); w0.y = pack2(a0[2], a0[3]);
            uint2 w1; w1.x = pack2(a1[0], a1[1]); w1.y = pack2(a1[2], a1[3]);
            uint2 w2; w2.x = pack2(a2[0], a2[1]); w2.y = pack2(a2[2], a2[3]);
            ((uint2*)&tb3[0 * GR + gi + m])[half] = w0;
            ((uint2*)&tb3[1 * GR + gi + m])[half] = w1;
            ((uint2*)&tb3[2 * GR + gi + m])[half] = w2;
            f32x4 bv = *(const f32x4*)&nbf[m * DIM + u0];
            f32x4 b2v = *(const f32x4*)&nb2f[m * DIM + u0];
            f32x4 x0;
#pragma unroll
            for (int q = 0; q < 4; ++q)
                x0[q] = a[q] * C9f + b2v[q] * C8f + bv[q] * C7f + ((u0 + q == m) ? C6f : 0.0f);
            wlds3s(XSu, m, u0, x0);
        } }
    __syncthreads();

    // ---- MM3: X1 = X0*B3 + (I/6 + B/24 + B2/120) ----
    mmS<false>(tb3, XSu, acc, wr, wc, lr, lg);
    __syncthreads();
#pragma unroll
    for (int i = 0; i < 2; ++i) { int u0 = wr + i * 16 + 4 * lg;
#pragma unroll
        for (int j = 0; j < 2; ++j) { int m = wc + j * 16 + lr;
            f32x4 bv = *(const f32x4*)&nbf[m * DIM + u0];
            f32x4 b2v = *(const f32x4*)&nb2f[m * DIM + u0];
            f32x4 x1;
#pragma unroll
            for (int q = 0; q < 4; ++q)
                x1[q] = acc[i][j][q] + bv[q] * (1.0f / 24.0f) + b2v[q] * (1.0f / 120.0f)
                      + ((u0 + q == m) ? (1.0f / 6.0f) : 0.0f);
            wlds3s(XSu, m, u0, x1);
        } }
    __syncthreads();

    // ---- MM4: X2 = X1*B3 + (I + B + B2/2) ----
    mmS<false>(tb3, XSu, acc, wr, wc, lr, lg);
    __syncthreads();
#pragma unroll
    for (int i = 0; i < 2; ++i) { int u0 = wr + i * 16 + 4 * lg;
#pragma unroll
        for (int j = 0; j < 2; ++j) { int m = wc + j * 16 + lr;
            f32x4 bv = *(const f32x4*)&nbf[m * DIM + u0];
            f32x4 b2v = *(const f32x4*)&nb2f[m * DIM + u0];
            f32x4 x2;
#pragma unroll
            for (int q = 0; q < 4; ++q)
                x2[q] = acc[i][j][q] + bv[q] + b2v[q] * 0.5f + ((u0 + q == m) ? 1.0f : 0.0f);
            wlds3s(XSu, m, u0, x2);
        } }
    __syncthreads();

    // ---- 8 squarings, entirely in LDS ----
    for (int sq = 0; sq < 8; ++sq) {
        mmS<true>(nullptr, XSu, acc, wr, wc, lr, lg);
        __syncthreads();
        if (sq < 7) {
#pragma unroll
            for (int i = 0; i < 2; ++i) { int u0 = wr + i * 16 + 4 * lg;
#pragma unroll
                for (int j = 0; j < 2; ++j) wlds3s(XSu, wc + j * 16 + lr, u0, acc[i][j]);
            }
            __syncthreads();
        } else {
            // acc = exp(herm).  T_b = exp^T:  TT[b] = T(T_b) = exp (straight);
            // TN[b] = N(T_b) = exp^T (transposed).  2-split via standard-layout
            // LDS planes 0,1, then existing copyN/copyT.
#pragma unroll
            for (int i = 0; i < 2; ++i) { int u0 = wr + i * 16 + 4 * lg; int half = (u0 >> 2) & 1;
#pragma unroll
                for (int j = 0; j < 2; ++j) { int m = wc + j * 16 + lr;
                    u16 h[4], l[4];
#pragma unroll
                    for (int q = 0; q < 4; ++q) split2(acc[i][j][q], h[q], l[q]);
                    uint2 hv; hv.x = pack2(h[0], h[1]); hv.y = pack2(h[2], h[3]);
                    uint2 lv; lv.x = pack2(l[0], l[1]); lv.y = pack2(l[2], l[3]);
                    int base = m * 16 + ((u0 >> 3) ^ (m & 7));
                    ((uint2*)&XL[0 * GR + base])[half] = hv;
                    ((uint2*)&XL[1 * GR + base])[half] = lv;
                } }
            __syncthreads();
            copyN(XL, XL + GR, TTh + (size_t)b * GR, TTl + (size_t)b * GR);
            copyT(XL, XL + GR, TNh + (size_t)b * GR, TNl + (size_t)b * GR);
        }
    }
}

// ============================================================================
// Phase B1: chains for v in [4,32) (+ identity plane).  29 blocks x 256 thr.
// V(v) = T_{b0} * T_{b1} * ... (bits LSB-first, leading 1 dropped).
// ============================================================================
__global__ __launch_bounds__(256) void chain_kernel(u16* TThp, u16* TTlp, u16* TNhp, u16* TNlp,
                                                    int schemeA) {
    __shared__ uint4 Mh[GR], Ml[GR];
    uint4* TTh = (uint4*)TThp; uint4* TTl = (uint4*)TTlp;
    uint4* TNh = (uint4*)TNhp; uint4* TNl = (uint4*)TNlp;
    int b = blockIdx.x;
    if (b == 28) {                           // identity N-plane
        int id = schemeA ? 274 : 126;
        for (int s = threadIdx.x; s < GR; s += 256) {
            int g = s >> 7, row = s & 127;
            u16 h[8];
#pragma unroll
            for (int k = 0; k < 8; ++k) h[k] = (g * 8 + k == row) ? (u16)0x3F80 : (u16)0;
            TNh[(size_t)id * GR + s] = packu4(h);
            uint4 z; z.x = z.y = z.z = z.w = 0u;
            TNl[(size_t)id * GR + s] = z;
        }
        return;
    }
    int v = 4 + b;
    int nb = 31 - __clz(v);                  // path length
    int b0 = v & 1;
    stage_lds(TNh + (size_t)b0 * GR, TNl + (size_t)b0 * GR, Mh, Ml);
    __syncthreads();
    for (int t = 1; t < nb; ++t) {
        int bt = (v >> t) & 1;
        f32x4 acc[4][4] = {};
        mm2<true>(TTh + (size_t)bt * GR, TTl + (size_t)bt * GR, Mh, Ml, acc);
        __syncthreads();
        acc_to_lds2(acc, Mh, Ml);
        __syncthreads();
    }
    copyT(Mh, Ml, TTh + (size_t)(v - 2) * GR, TTl + (size_t)(v - 2) * GR);
    bool needN = schemeA ? (v >= 16) : true;
    if (needN) {
        int tn = schemeA ? (v - 14) : (v - 2);
        copyN(Mh, Ml, TNh + (size_t)tn * GR, TNl + (size_t)tn * GR);
    }
}

// ============================================================================
// Phase B2: all remaining v in one launch: V(v) = C4(v&15) * V(v>>4).
// schemeA: v in [32,512), 480 blocks.  schemeB: v in [32,128), 96 blocks.
// ============================================================================
__global__ __launch_bounds__(256) void pair_kernel(u16* TThp, u16* TTlp, u16* TNhp, u16* TNlp,
                                                   int schemeA) {
    __shared__ uint4 Mh[GR], Ml[GR];
    uint4* TTh = (uint4*)TThp; uint4* TTl = (uint4*)TTlp;
    uint4* TNh = (uint4*)TNhp; uint4* TNl = (uint4*)TNlp;
    int v = 32 + blockIdx.x;
    int c4 = v & 15;
    int tnb = schemeA ? (2 + c4) : (14 + c4);          // slot of N(V(16+c4))
    int tta = (v >> 4) - 2;                            // slot of T(V(v>>4))
    f32x4 acc[4][4] = {};
    mm2<false>(TTh + (size_t)tta * GR, TTl + (size_t)tta * GR,
               TNh + (size_t)tnb * GR, TNl + (size_t)tnb * GR, acc);
    bool wN = schemeA ? (v >= 256) : true;
    bool wT = schemeA ? (v < 256) : true;
    if (wN) {
        int tn = schemeA ? (18 + (v - 256)) : (v - 2);
        acc_to_gN(acc, TNh + (size_t)tn * GR, TNl + (size_t)tn * GR);
    }
    if (wT) {
        acc_to_lds2(acc, Mh, Ml);
        __syncthreads();
        copyT(Mh, Ml, TTh + (size_t)(v - 2) * GR, TTl + (size_t)(v - 2) * GR);
    }
}

// ============================================================================
// Phase C: one block per position.
// schemeA: maps(p) = C8(p&255) * V(p>>8) -> ONE matmul, operands from global,
//          zero LDS.  schemeB: 6-bit chunks, <=2 matmuls, 64 KB dynamic LDS.
// ============================================================================
__global__ __launch_bounds__(256) void final_kernel(const u16* TThp, const u16* TTlp,
                                                    const u16* TNhp, const u16* TNlp,
                                                    const int* __restrict__ uq,
                                                    float* __restrict__ out, int schemeA) {
    extern __shared__ uint4 FL[];
    const uint4* TTh = (const uint4*)TThp; const uint4* TTl = (const uint4*)TTlp;
    const uint4* TNh = (const uint4*)TNhp; const uint4* TNl = (const uint4*)TNlp;
    float* O = out + (size_t)blockIdx.x * MAT;
    unsigned p = (unsigned)uq[blockIdx.x];

    if (p < 2u) {                                      // identity output
        for (int s = threadIdx.x; s < 4096; s += 256) {
            int r = s >> 5, c0 = (s & 31) * 4;
            float4 v; v.x = v.y = v.z = v.w = 0.f;
            int d = r - c0;
            if (d == 0) v.x = 1.f; else if (d == 1) v.y = 1.f;
            else if (d == 2) v.z = 1.f; else if (d == 3) v.w = 1.f;
            *(float4*)&O[r * DIM + c0] = v;
        }
        return;
    }

    const uint4 *pah, *pal, *pbh, *pbl;
    int m3 = -1;
    if (schemeA) {
        const int id = 274;
        if (p < 256u) {                                // out = V(p) * I
            pah = TTh + (size_t)(p - 2) * GR; pal = TTl + (size_t)(p - 2) * GR;
            pbh = TNh + (size_t)id * GR;      pbl = TNl + (size_t)id * GR;
        } else {
            int lo = (int)(p & 255u); unsigned hi = p >> 8;
            pbh = TNh + (size_t)(18 + lo) * GR; pbl = TNl + (size_t)(18 + lo) * GR;
            if (hi >= 2u) { pah = TTh + (size_t)(hi - 2) * GR; pal = TTl + (size_t)(hi - 2) * GR; }
            else          { pah = TNh + (size_t)id * GR;       pal = TNl + (size_t)id * GR; }
        }
    } else {
        int f[3]; int m = 0; unsigned q = p;
        while (q >= 128u) { f[m++] = 64 + (int)(q & 63u); q >>= 6; }
        f[m++] = (int)q;
        if (m == 1) {                                  // out = V(p) directly
            const uint4* sh = TNh + (size_t)(f[0] - 2) * GR;
            const uint4* sl = TNl + (size_t)(f[0] - 2) * GR;
            for (int s = threadIdx.x; s < GR; s += 256) {
                int row = s >> 4, g = s & 15;
                uint4 H = sh[g * 128 + row], L = sl[g * 128 + row];
                float4 o0, o1;
                o0.x = bf2f((u16)(H.x & 0xffff)) + bf2f((u16)(L.x & 0xffff));
                o0.y = bf2f((u16)(H.x >> 16))    + bf2f((u16)(L.x >> 16));
                o0.z = bf2f((u16)(H.y & 0xffff)) + bf2f((u16)(L.y & 0xffff));
                o0.w = bf2f((u16)(H.y >> 16))    + bf2f((u16)(L.y >> 16));
                o1.x = bf2f((u16)(H.z & 0xffff)) + bf2f((u16)(L.z & 0xffff));
                o1.y = bf2f((u16)(H.z >> 16))    + bf2f((u16)(L.z >> 16));
                o1.z = bf2f((u16)(H.w & 0xffff)) + bf2f((u16)(L.w & 0xffff));
                o1.w = bf2f((u16)(H.w >> 16))    + bf2f((u16)(L.w >> 16));
                *(float4*)&O[row * DIM + g * 8] = o0;
                *(float4*)&O[row * DIM + g * 8 + 4] = o1;
            }
            return;
        }
        pbh = TNh + (size_t)(f[0] - 2) * GR; pbl = TNl + (size_t)(f[0] - 2) * GR;
        pah = TTh + (size_t)(f[1] - 2) * GR; pal = TTl + (size_t)(f[1] - 2) * GR;
        if (m == 3) m3 = f[2] - 2;
    }

    f32x4 acc[4][4] = {};
    mm2<false>(pah, pal, pbh, pbl, acc);
    if (m3 < 0) { acc_to_out(acc, O); return; }
    acc_to_lds2(acc, FL, FL + GR);
    __syncthreads();
    f32x4 a2[4][4] = {};
    mm2<true>(TTh + (size_t)m3 * GR, TTl + (size_t)m3 * GR, FL, FL + GR, a2);
    acc_to_out(a2, O);
}

// ============================================================================
// launch
// ============================================================================
extern "C" void kernel_launch(void* const* d_in, const int* in_sizes, int n_in,
                              void* d_out, int out_size, void* d_ws, size_t ws_size,
                              hipStream_t stream) {
    const int*   uq = (const int*)d_in[0];
    const float* P  = (const float*)d_in[1];
    float* out = (float*)d_out;

    // scheme A (8/8 split, 1-matmul final) needs ~33.9 MiB; else 6-bit scheme (~16.6 MiB)
    const size_t needA = (size_t)(2 * 254 + 2 * 275 + 18) * MAT * 2 + (size_t)4 * MAT * 4;
    const bool A = ws_size >= needA;
    const int nTT = A ? 254 : 126;
    const int nTN = A ? 275 : 127;

    u16* TTh = (u16*)d_ws;
    u16* TTl = TTh + (size_t)nTT * MAT;
    u16* TNh = TTl + (size_t)nTT * MAT;
    u16* TNl = TNh + (size_t)nTN * MAT;
    u16* TB  = TNl + (size_t)nTN * MAT;     // [2][3][MAT]
    u16* TB3 = TB  + (size_t)6 * MAT;
    u16* XTg = TB3 + (size_t)6 * MAT;       // (retired scratch, kept for layout stability)
    float* NBf  = (float*)(XTg + (size_t)6 * MAT);
    float* NB2f = NBf + 2 * MAT;

    expm_kernel<<<2, 1024, 0, stream>>>(P, NBf, NB2f, TB, TB3, TTh, TTl, TNh, TNl);
    chain_kernel<<<29, 256, 0, stream>>>(TTh, TTl, TNh, TNl, (int)A);
    pair_kernel<<<A ? 480 : 96, 256, 0, stream>>>(TTh, TTl, TNh, TNl, (int)A);
    final_kernel<<<1024, 256, A ? 0 : 65536, stream>>>(TTh, TTl, TNh, TNl, uq, out, (int)A);
}

// Round 4
// 138.281 us; speedup vs baseline: 1.3634x; 1.1364x over previous
//
#include <hip/hip_runtime.h>

typedef unsigned int uint32;
typedef unsigned short u16;
typedef __attribute__((ext_vector_type(8))) short bf16x8;
typedef __attribute__((ext_vector_type(4))) float f32x4;
typedef __attribute__((ext_vector_type(2))) uint32 u32x2;
typedef __attribute__((ext_vector_type(4))) uint32 u32x4;

#define DIM 128
#define MAT (DIM * DIM)
#define GR  2048                 // uint4 granules per 128x128 bf16 plane (32 KB)
#define PLANE 16384              // u16 elements per plane
#define MFMA __builtin_amdgcn_mfma_f32_16x16x32_bf16

// Plane formats:
//  FmtG (global bf16 planes): uint4 granule index = g*128 + row   (g = col/8)
//  LDS standard (chain/pair/final + expm final staging): uint4 idx = row*16 + (g ^ (row&7))
//  LDS subtiled (expm internal, serves BOTH mfma operands):
//    element (r,c) at  ((r>>2)*8 + (c>>4))*64 + (r&3)*16 + (c&15)
//    - row fragment (fixed r, 8 consecutive c): contiguous 16 B  -> ds_read_b128
//    - col fragment (fixed c, consecutive r):   ds_read_b64_tr_b16.
//      tr_b16 semantics (verified round 3): result = column (addr>>3)&15 of the
//      4x16 row-major bf16 tile at (addr & ~127); so pass addr =
//      subtile_base_bytes + 8*col_in_subtile.
// Core semantic (verified): with a-frags from PA rows u and b-frags from PB
// rows w,  D[u][w] = sum_k PA[u][k]*PB[w][k]; the f32x4 acc spans 4
// consecutive u at fixed w.  For out = L*R: PA = T(R), PB = N(L), out[w][u]=D.
//
// Numerics (round 4): scale 1/64 + 6 squarings (||herm|| ~ 37 analytically;
// deg-9 remainder at ||B||<=1.1 is <1e-6 even pessimistically).  Squarings
// run 2-split/3-pass (chain amplifies split error by 2^6=64; 64*2^-18 ~ 1e-4,
// invisible at the 0.019 threshold).  Taylor phases stay 3-split/6-pass.

// ---------------- scalar helpers ----------------
__device__ __forceinline__ u16 f2bf(float x) {
    uint32 u = __float_as_uint(x);
    u += 0x7fffu + ((u >> 16) & 1u);
    return (u16)(u >> 16);
}
__device__ __forceinline__ float bf2f(u16 h) { return __uint_as_float(((uint32)h) << 16); }
__device__ __forceinline__ void split2(float x, u16& a0, u16& a1) {
    a0 = f2bf(x); a1 = f2bf(x - bf2f(a0));
}
__device__ __forceinline__ void split3(float x, u16& a0, u16& a1, u16& a2) {
    a0 = f2bf(x); float r = x - bf2f(a0);
    a1 = f2bf(r); float r2 = r - bf2f(a1);
    a2 = f2bf(r2);
}
__device__ __forceinline__ uint32 pack2(u16 a, u16 b) { return (uint32)a | ((uint32)b << 16); }
__device__ __forceinline__ uint4 packu4(const u16 (&a)[8]) {
    uint4 v; v.x = pack2(a[0], a[1]); v.y = pack2(a[2], a[3]);
    v.z = pack2(a[4], a[5]); v.w = pack2(a[6], a[7]); return v;
}
__device__ __forceinline__ uint32 comp4(const uint4& v, int c) {
    return c == 0 ? v.x : c == 1 ? v.y : c == 2 ? v.z : v.w;
}
// 8x8 u16 transpose in registers (all indices compile-time under unroll)
__device__ __forceinline__ void transp8(const uint4 (&in)[8], uint4 (&out)[8]) {
#pragma unroll
    for (int c = 0; c < 8; ++c) {
        u16 o[8];
#pragma unroll
        for (int k = 0; k < 8; ++k) o[k] = (u16)(comp4(in[k], c >> 1) >> ((c & 1) * 16));
        out[c].x = pack2(o[0], o[1]); out[c].y = pack2(o[2], o[3]);
        out[c].z = pack2(o[4], o[5]); out[c].w = pack2(o[6], o[7]);
    }
}

// ---------------- 4-wave (256 thr) 2-split 3-pass matmul core ----------------
template<bool PBLDS>
__device__ __forceinline__ void mm2(const uint4* __restrict__ pah, const uint4* __restrict__ pal,
                                    const uint4* __restrict__ pbh, const uint4* __restrict__ pbl,
                                    f32x4 (&acc)[4][4]) {
    const int tid = threadIdx.x, lane = tid & 63, w = tid >> 6;
    const int wr = (w >> 1) * 64, wc = (w & 1) * 64, lr = lane & 15, lg = lane >> 4;
#pragma unroll 1
    for (int kb = 0; kb < 4; ++kb) {
        const int g = kb * 4 + lg;
        bf16x8 ah[4], al[4], bh[4], bl[4];
#pragma unroll
        for (int t = 0; t < 4; ++t) {
            int ra = wr + t * 16 + lr;
            ah[t] = *(const bf16x8*)&pah[g * 128 + ra];
            al[t] = *(const bf16x8*)&pal[g * 128 + ra];
            int rb = wc + t * 16 + lr;
            int ib = PBLDS ? (rb * 16 + (g ^ (rb & 7))) : (g * 128 + rb);
            bh[t] = *(const bf16x8*)&pbh[ib];
            bl[t] = *(const bf16x8*)&pbl[ib];
        }
#pragma unroll
        for (int i = 0; i < 4; ++i)
#pragma unroll
            for (int j = 0; j < 4; ++j) {
                acc[i][j] = MFMA(ah[i], bh[j], acc[i][j], 0, 0, 0);
                acc[i][j] = MFMA(ah[i], bl[j], acc[i][j], 0, 0, 0);
                acc[i][j] = MFMA(al[i], bh[j], acc[i][j], 0, 0, 0);
            }
    }
}

// acc -> LDS pair (swizzled N-form: row w holds result[w][*])
__device__ __forceinline__ void acc_to_lds2(const f32x4 (&acc)[4][4], uint4* Mh, uint4* Ml) {
    const int tid = threadIdx.x, lane = tid & 63, w = tid >> 6;
    const int wr = (w >> 1) * 64, wc = (w & 1) * 64, lr = lane & 15, lg = lane >> 4;
#pragma unroll
    for (int i = 0; i < 4; ++i) {
        int u0 = wr + i * 16 + 4 * lg, half = (u0 >> 2) & 1, gq = u0 >> 3;
#pragma unroll
        for (int j = 0; j < 4; ++j) {
            int m = wc + j * 16 + lr;
            u16 h[4], l[4];
#pragma unroll
            for (int q = 0; q < 4; ++q) split2(acc[i][j][q], h[q], l[q]);
            uint2 hv; hv.x = pack2(h[0], h[1]); hv.y = pack2(h[2], h[3]);
            uint2 lv; lv.x = pack2(l[0], l[1]); lv.y = pack2(l[2], l[3]);
            int base = m * 16 + (gq ^ (m & 7));
            ((uint2*)&Mh[base])[half] = hv;
            ((uint2*)&Ml[base])[half] = lv;
        }
    }
}

// acc -> global FmtG pair (N-form rows)
__device__ __forceinline__ void acc_to_gN(const f32x4 (&acc)[4][4], uint4* nh, uint4* nl) {
    const int tid = threadIdx.x, lane = tid & 63, w = tid >> 6;
    const int wr = (w >> 1) * 64, wc = (w & 1) * 64, lr = lane & 15, lg = lane >> 4;
#pragma unroll
    for (int i = 0; i < 4; ++i) {
        int u0 = wr + i * 16 + 4 * lg, half = (u0 >> 2) & 1, gq = u0 >> 3;
#pragma unroll
        for (int j = 0; j < 4; ++j) {
            int m = wc + j * 16 + lr;
            u16 h[4], l[4];
#pragma unroll
            for (int q = 0; q < 4; ++q) split2(acc[i][j][q], h[q], l[q]);
            uint2 hv; hv.x = pack2(h[0], h[1]); hv.y = pack2(h[2], h[3]);
            uint2 lv; lv.x = pack2(l[0], l[1]); lv.y = pack2(l[2], l[3]);
            int base = gq * 128 + m;
            ((uint2*)&nh[base])[half] = hv;
            ((uint2*)&nl[base])[half] = lv;
        }
    }
}

// acc -> fp32 output (out[w][u])
__device__ __forceinline__ void acc_to_out(const f32x4 (&acc)[4][4], float* O) {
    const int tid = threadIdx.x, lane = tid & 63, w = tid >> 6;
    const int wr = (w >> 1) * 64, wc = (w & 1) * 64, lr = lane & 15, lg = lane >> 4;
#pragma unroll
    for (int i = 0; i < 4; ++i) {
        int u0 = wr + i * 16 + 4 * lg;
#pragma unroll
        for (int j = 0; j < 4; ++j) {
            int m = wc + j * 16 + lr;
            *(f32x4*)&O[m * DIM + u0] = acc[i][j];
        }
    }
}

// ---------------- plane copies ----------------
// global FmtG -> LDS swizzled (content preserved, N-form)
__device__ __forceinline__ void stage_lds(const uint4* sh, const uint4* sl, uint4* Mh, uint4* Ml) {
    for (int s = threadIdx.x; s < GR; s += blockDim.x) {
        int g = s >> 7, row = s & 127;
        int d = row * 16 + (g ^ (row & 7));
        Mh[d] = sh[s]; Ml[d] = sl[s];
    }
}
// LDS pair -> global FmtG pair, straight (N content)
__device__ __forceinline__ void copyN(const uint4* Mh, const uint4* Ml, uint4* dh, uint4* dl) {
    for (int s2 = threadIdx.x; s2 < 2 * GR; s2 += blockDim.x) {
        const uint4* src = (s2 & GR) ? Ml : Mh;
        uint4* dst = (s2 & GR) ? dl : dh;
        int s = s2 & (GR - 1);
        int g = s >> 7, row = s & 127;
        dst[s] = src[row * 16 + (g ^ (row & 7))];
    }
}
// LDS pair -> global FmtG pair, TRANSPOSED (dst[r][c] = src[c][r])
__device__ __forceinline__ void copyT(const uint4* Mh, const uint4* Ml, uint4* dh, uint4* dl) {
    for (int tk = threadIdx.x; tk < 512; tk += blockDim.x) {
        const uint4* src = (tk & 256) ? Ml : Mh;
        uint4* dst = (tk & 256) ? dl : dh;
        int t = tk & 255, br = t >> 4, bc = t & 15;
        uint4 in[8], out[8];
#pragma unroll
        for (int k = 0; k < 8; ++k) { int r = br * 8 + k; in[k] = src[r * 16 + (bc ^ (r & 7))]; }
        transp8(in, out);
#pragma unroll
        for (int k = 0; k < 8; ++k) dst[br * 128 + bc * 8 + k] = out[k];
    }
}

// ============================================================================
// Phase A: fused expm.  2 blocks x 1024 threads (16 waves, wave grid u:4 x w:4,
// 2x2 output tiles per wave).
// B = (P-P^T)/64; PS deg-9 Taylor (B2,B3 + 2 Horner steps); 6 squarings.
// X lives in LDS in the 4x16-subtiled layout which serves BOTH operands:
// B-op fragments via contiguous ds_read_b128, A-op (transposed) fragments via
// hardware ds_read_b64_tr_b16 -- no T-form materialization, no global
// round-trip in the squaring loop.  Taylor phases 3-split/6-pass; squarings
// 2-split/3-pass.  A-op for MM2..MM4 comes from once-written global FmtG
// scratch (TB = -B = B^T, TB3 = -B3 = B3^T by skewness).
// ============================================================================

// NSP-split write of one f32x4 quad (row m, cols u0..u0+3) into subtiled LDS
__device__ __forceinline__ void wlds3s(u16* XSu, int m, int u0, f32x4 v) {
    u16 a0[4], a1[4], a2[4];
#pragma unroll
    for (int q = 0; q < 4; ++q) split3(v[q], a0[q], a1[q], a2[q]);
    int e = ((m >> 2) * 8 + (u0 >> 4)) * 64 + (m & 3) * 16 + (u0 & 15);
    uint2 w0; w0.x = pack2(a0[0], a0[1]); w0.y = pack2(a0[2], a0[3]);
    uint2 w1; w1.x = pack2(a1[0], a1[1]); w1.y = pack2(a1[2], a1[3]);
    uint2 w2; w2.x = pack2(a2[0], a2[1]); w2.y = pack2(a2[2], a2[3]);
    *(uint2*)&XSu[0 * PLANE + e] = w0;
    *(uint2*)&XSu[1 * PLANE + e] = w1;
    *(uint2*)&XSu[2 * PLANE + e] = w2;
}
__device__ __forceinline__ void wlds2s(u16* XSu, int m, int u0, f32x4 v) {
    u16 a0[4], a1[4];
#pragma unroll
    for (int q = 0; q < 4; ++q) split2(v[q], a0[q], a1[q]);
    int e = ((m >> 2) * 8 + (u0 >> 4)) * 64 + (m & 3) * 16 + (u0 & 15);
    uint2 w0; w0.x = pack2(a0[0], a0[1]); w0.y = pack2(a0[2], a0[3]);
    uint2 w1; w1.x = pack2(a1[0], a1[1]); w1.y = pack2(a1[2], a1[3]);
    *(uint2*)&XSu[0 * PLANE + e] = w0;
    *(uint2*)&XSu[1 * PLANE + e] = w1;
}

// 16-wave NSP-split matmul core.  ATR: A-op via ds_read_b64_tr_b16 from
// subtiled LDS (PA = T(X)); else A-op from global FmtG (pa).  B-op always
// subtiled LDS.  NSP==3: 6-pass (hh,hm,mh,mm,hl,lh); NSP==2: 3-pass (hh,hl,lh).
template<bool ATR, int NSP>
__device__ __forceinline__ void mmS(const uint4* __restrict__ pa, const u16* __restrict__ XSu,
                                    f32x4 (&acc)[2][2], int wr, int wc, int lr, int lg) {
#pragma unroll
    for (int i = 0; i < 2; ++i)
#pragma unroll
        for (int j = 0; j < 2; ++j) { f32x4 z = {0.f, 0.f, 0.f, 0.f}; acc[i][j] = z; }
    const uint32 lds_base = (uint32)(size_t)(const void*)XSu;
#pragma unroll 1
    for (int kb = 0; kb < 4; ++kb) {
        const int g = kb * 4 + lg;
        u32x2 t0[2][NSP], t1[2][NSP];
        bf16x8 aa[2][NSP], bb[2][NSP];
        if (ATR) {
            // column ra = wr + t*16 + lr of X, rows 8g..8g+7.
            // tile = subtile (16g + wr/16 + t) at byte (16g + wr/16 + t)*128;
            // column select = (addr>>3)&15 = lr  ->  addr = tile_base + 8*lr.
            // rows 4..7 live one subtile-row (8 subtiles = 1024 B) ahead.
#pragma unroll
            for (int t = 0; t < 2; ++t) {
                uint32 ba = lds_base + (uint32)(((16 * g + (wr >> 4) + t) << 7) + 8 * lr);
#pragma unroll
                for (int sp = 0; sp < NSP; ++sp) {
                    asm volatile("ds_read_b64_tr_b16 %0, %2\n\t"
                                 "ds_read_b64_tr_b16 %1, %2 offset:1024"
                                 : "=&v"(t0[t][sp]), "=&v"(t1[t][sp])
                                 : "v"(ba + (uint32)(sp * 2 * PLANE)));
                }
            }
        } else {
#pragma unroll
            for (int t = 0; t < 2; ++t) {
                int ra = wr + t * 16 + lr;
#pragma unroll
                for (int sp = 0; sp < NSP; ++sp) aa[t][sp] = *(const bf16x8*)&pa[sp * GR + g * 128 + ra];
            }
        }
#pragma unroll
        for (int t = 0; t < 2; ++t) {
            int rb = wc + t * 16 + lr;
            int e = ((rb >> 2) * 8 + (g >> 1)) * 64 + (rb & 3) * 16 + (g & 1) * 8;
#pragma unroll
            for (int sp = 0; sp < NSP; ++sp) bb[t][sp] = *(const bf16x8*)&XSu[sp * PLANE + e];
        }
        if (ATR) {
            // rule #18: drain asm ds_reads, then fence scheduling so the fragment
            // assembly + MFMAs cannot be hoisted above the wait.
            asm volatile("s_waitcnt lgkmcnt(0)" ::: "memory");
            __builtin_amdgcn_sched_barrier(0);
#pragma unroll
            for (int t = 0; t < 2; ++t)
#pragma unroll
                for (int sp = 0; sp < NSP; ++sp) {
                    u32x4 v; v.x = t0[t][sp].x; v.y = t0[t][sp].y;
                    v.z = t1[t][sp].x; v.w = t1[t][sp].y;
                    aa[t][sp] = *(bf16x8*)&v;
                }
        }
#pragma unroll
        for (int i = 0; i < 2; ++i)
#pragma unroll
            for (int j = 0; j < 2; ++j) {
                acc[i][j] = MFMA(aa[i][0], bb[j][0], acc[i][j], 0, 0, 0);
                acc[i][j] = MFMA(aa[i][0], bb[j][1], acc[i][j], 0, 0, 0);
                acc[i][j] = MFMA(aa[i][1], bb[j][0], acc[i][j], 0, 0, 0);
                if (NSP == 3) {
                    acc[i][j] = MFMA(aa[i][1], bb[j][1], acc[i][j], 0, 0, 0);
                    acc[i][j] = MFMA(aa[i][0], bb[j][2], acc[i][j], 0, 0, 0);
                    acc[i][j] = MFMA(aa[i][2], bb[j][0], acc[i][j], 0, 0, 0);
                }
            }
    }
}

__global__ __launch_bounds__(1024) void expm_kernel(
        const float* __restrict__ P, float* __restrict__ NBf, float* __restrict__ NB2f,
        u16* TBp, u16* TB3p,
        u16* TThp, u16* TTlp, u16* TNhp, u16* TNlp) {
    __shared__ uint4 XL[3 * GR];           // 96 KB
    u16* XSu = (u16*)XL;
    const int b = blockIdx.x, tid = threadIdx.x;
    const int lane = tid & 63, w = tid >> 6;
    const int wr = (w >> 2) * 32, wc = (w & 3) * 32, lr = lane & 15, lg = lane >> 4;
    const float* Pm = P + b * MAT;
    float* nbf = NBf + b * MAT;
    float* nb2f = NB2f + b * MAT;
    uint4* tb  = (uint4*)TBp  + (size_t)b * 3 * GR;
    uint4* tb3 = (uint4*)TB3p + (size_t)b * 3 * GR;
    uint4* TTh = (uint4*)TThp; uint4* TTl = (uint4*)TTlp;
    uint4* TNh = (uint4*)TNhp; uint4* TNl = (uint4*)TNlp;

    const float C6f = 1.0f / 720.0f, C7f = 1.0f / 5040.0f, C8f = 1.0f / 40320.0f, C9f = 1.0f / 362880.0f;

    // ---- prep: B = (P - P^T)/64 -> LDS(subtiled) + fp32 NBf + global TB (=-B, FmtG) ----
    for (int s = tid; s < GR; s += 1024) {
        int r = s >> 4, g = s & 15;
        float vv[8];
#pragma unroll
        for (int k = 0; k < 8; ++k) {
            int c = g * 8 + k;
            vv[k] = (Pm[r * DIM + c] - Pm[c * DIM + r]) * (1.0f / 64.0f);
        }
        float4 f0; f0.x = vv[0]; f0.y = vv[1]; f0.z = vv[2]; f0.w = vv[3];
        float4 f1; f1.x = vv[4]; f1.y = vv[5]; f1.z = vv[6]; f1.w = vv[7];
        *(float4*)&nbf[r * DIM + g * 8] = f0;
        *(float4*)&nbf[r * DIM + g * 8 + 4] = f1;
        u16 s0[8], s1[8], s2[8];
#pragma unroll
        for (int k = 0; k < 8; ++k) split3(vv[k], s0[k], s1[k], s2[k]);
        int d = ((r >> 2) * 8 + (g >> 1)) * 64 + (r & 3) * 16 + (g & 1) * 8;
        *(uint4*)&XSu[0 * PLANE + d] = packu4(s0);
        *(uint4*)&XSu[1 * PLANE + d] = packu4(s1);
        *(uint4*)&XSu[2 * PLANE + d] = packu4(s2);
        // negate by sign-flip
#pragma unroll
        for (int k = 0; k < 8; ++k) { s0[k] ^= 0x8000; s1[k] ^= 0x8000; s2[k] ^= 0x8000; }
        int gi = g * 128 + r;
        tb[0 * GR + gi] = packu4(s0); tb[1 * GR + gi] = packu4(s1); tb[2 * GR + gi] = packu4(s2);
    }
    __syncthreads();

    f32x4 acc[2][2];

    // ---- MM1: B2 = B*B  (A = T(B) via tr-reads) ----
    mmS<true, 3>(nullptr, XSu, acc, wr, wc, lr, lg);
    __syncthreads();
#pragma unroll
    for (int i = 0; i < 2; ++i) { int u0 = wr + i * 16 + 4 * lg;
#pragma unroll
        for (int j = 0; j < 2; ++j) { int m = wc + j * 16 + lr;
            *(f32x4*)&nb2f[m * DIM + u0] = acc[i][j];
            wlds3s(XSu, m, u0, acc[i][j]);
        } }
    __syncthreads();

    // ---- MM2: B3 = B2*B ; TB3 = -B3 ; X0 -> LDS ----
    mmS<false, 3>(tb, XSu, acc, wr, wc, lr, lg);
    __syncthreads();
#pragma unroll
    for (int i = 0; i < 2; ++i) { int u0 = wr + i * 16 + 4 * lg; int half = (u0 >> 2) & 1; int gi = (u0 >> 3) * 128;
#pragma unroll
        for (int j = 0; j < 2; ++j) { int m = wc + j * 16 + lr;
            f32x4 a = acc[i][j];
            u16 a0[4], a1[4], a2[4];
#pragma unroll
            for (int q = 0; q < 4; ++q) split3(-a[q], a0[q], a1[q], a2[q]);
            uint2 w0; w0.x = pack2(a0[0], a0[1]); w0.y = pack2(a0[2], a0[3]);
            uint2 w1; w1.x = pack2(a1[0], a1[1]); w1.y = pack2(a1[2], a1[3]);
            uint2 w2; w2.x = pack2(a2[0], a2[1]); w2.y = pack2(a2[2], a2[3]);
            ((uint2*)&tb3[0 * GR + gi + m])[half] = w0;
            ((uint2*)&tb3[1 * GR + gi + m])[half] = w1;
            ((uint2*)&tb3[2 * GR + gi + m])[half] = w2;
            f32x4 bv = *(const f32x4*)&nbf[m * DIM + u0];
            f32x4 b2v = *(const f32x4*)&nb2f[m * DIM + u0];
            f32x4 x0;
#pragma unroll
            for (int q = 0; q < 4; ++q)
                x0[q] = a[q] * C9f + b2v[q] * C8f + bv[q] * C7f + ((u0 + q == m) ? C6f : 0.0f);
            wlds3s(XSu, m, u0, x0);
        } }
    __syncthreads();

    // ---- MM3: X1 = X0*B3 + (I/6 + B/24 + B2/120) ----
    mmS<false, 3>(tb3, XSu, acc, wr, wc, lr, lg);
    __syncthreads();
#pragma unroll
    for (int i = 0; i < 2; ++i) { int u0 = wr + i * 16 + 4 * lg;
#pragma unroll
        for (int j = 0; j < 2; ++j) { int m = wc + j * 16 + lr;
            f32x4 bv = *(const f32x4*)&nbf[m * DIM + u0];
            f32x4 b2v = *(const f32x4*)&nb2f[m * DIM + u0];
            f32x4 x1;
#pragma unroll
            for (int q = 0; q < 4; ++q)
                x1[q] = acc[i][j][q] + bv[q] * (1.0f / 24.0f) + b2v[q] * (1.0f / 120.0f)
                      + ((u0 + q == m) ? (1.0f / 6.0f) : 0.0f);
            wlds3s(XSu, m, u0, x1);
        } }
    __syncthreads();

    // ---- MM4: X2 = X1*B3 + (I + B + B2/2) ----
    mmS<false, 3>(tb3, XSu, acc, wr, wc, lr, lg);
    __syncthreads();
#pragma unroll
    for (int i = 0; i < 2; ++i) { int u0 = wr + i * 16 + 4 * lg;
#pragma unroll
        for (int j = 0; j < 2; ++j) { int m = wc + j * 16 + lr;
            f32x4 bv = *(const f32x4*)&nbf[m * DIM + u0];
            f32x4 b2v = *(const f32x4*)&nb2f[m * DIM + u0];
            f32x4 x2;
#pragma unroll
            for (int q = 0; q < 4; ++q)
                x2[q] = acc[i][j][q] + bv[q] + b2v[q] * 0.5f + ((u0 + q == m) ? 1.0f : 0.0f);
            wlds3s(XSu, m, u0, x2);
        } }
    __syncthreads();

    // ---- 6 squarings, entirely in LDS, 2-split (planes 0,1 of the 3-split
    //      X2 are exactly its 2-split, so the first iteration is seamless) ----
    for (int sq = 0; sq < 6; ++sq) {
        mmS<true, 2>(nullptr, XSu, acc, wr, wc, lr, lg);
        __syncthreads();
        if (sq < 5) {
#pragma unroll
            for (int i = 0; i < 2; ++i) { int u0 = wr + i * 16 + 4 * lg;
#pragma unroll
                for (int j = 0; j < 2; ++j) wlds2s(XSu, wc + j * 16 + lr, u0, acc[i][j]);
            }
            __syncthreads();
        } else {
            // acc = exp(herm).  T_b = exp^T:  TT[b] = T(T_b) = exp (straight);
            // TN[b] = N(T_b) = exp^T (transposed).  2-split via standard-layout
            // LDS planes 0,1, then existing copyN/copyT.
#pragma unroll
            for (int i = 0; i < 2; ++i) { int u0 = wr + i * 16 + 4 * lg; int half = (u0 >> 2) & 1;
#pragma unroll
                for (int j = 0; j < 2; ++j) { int m = wc + j * 16 + lr;
                    u16 h[4], l[4];
#pragma unroll
                    for (int q = 0; q < 4; ++q) split2(acc[i][j][q], h[q], l[q]);
                    uint2 hv; hv.x = pack2(h[0], h[1]); hv.y = pack2(h[2], h[3]);
                    uint2 lv; lv.x = pack2(l[0], l[1]); lv.y = pack2(l[2], l[3]);
                    int base = m * 16 + ((u0 >> 3) ^ (m & 7));
                    ((uint2*)&XL[0 * GR + base])[half] = hv;
                    ((uint2*)&XL[1 * GR + base])[half] = lv;
                } }
            __syncthreads();
            copyN(XL, XL + GR, TTh + (size_t)b * GR, TTl + (size_t)b * GR);
            copyT(XL, XL + GR, TNh + (size_t)b * GR, TNl + (size_t)b * GR);
        }
    }
}

// ============================================================================
// Phase B1: chains for v in [4,32) (+ identity plane).  29 blocks x 256 thr.
// V(v) = T_{b0} * T_{b1} * ... (bits LSB-first, leading 1 dropped).
// ============================================================================
__global__ __launch_bounds__(256) void chain_kernel(u16* TThp, u16* TTlp, u16* TNhp, u16* TNlp,
                                                    int schemeA) {
    __shared__ uint4 Mh[GR], Ml[GR];
    uint4* TTh = (uint4*)TThp; uint4* TTl = (uint4*)TTlp;
    uint4* TNh = (uint4*)TNhp; uint4* TNl = (uint4*)TNlp;
    int b = blockIdx.x;
    if (b == 28) {                           // identity N-plane
        int id = schemeA ? 274 : 126;
        for (int s = threadIdx.x; s < GR; s += 256) {
            int g = s >> 7, row = s & 127;
            u16 h[8];
#pragma unroll
            for (int k = 0; k < 8; ++k) h[k] = (g * 8 + k == row) ? (u16)0x3F80 : (u16)0;
            TNh[(size_t)id * GR + s] = packu4(h);
            uint4 z; z.x = z.y = z.z = z.w = 0u;
            TNl[(size_t)id * GR + s] = z;
        }
        return;
    }
    int v = 4 + b;
    int nb = 31 - __clz(v);                  // path length
    int b0 = v & 1;
    stage_lds(TNh + (size_t)b0 * GR, TNl + (size_t)b0 * GR, Mh, Ml);
    __syncthreads();
    for (int t = 1; t < nb; ++t) {
        int bt = (v >> t) & 1;
        f32x4 acc[4][4] = {};
        mm2<true>(TTh + (size_t)bt * GR, TTl + (size_t)bt * GR, Mh, Ml, acc);
        __syncthreads();
        acc_to_lds2(acc, Mh, Ml);
        __syncthreads();
    }
    copyT(Mh, Ml, TTh + (size_t)(v - 2) * GR, TTl + (size_t)(v - 2) * GR);
    bool needN = schemeA ? (v >= 16) : true;
    if (needN) {
        int tn = schemeA ? (v - 14) : (v - 2);
        copyN(Mh, Ml, TNh + (size_t)tn * GR, TNl + (size_t)tn * GR);
    }
}

// ============================================================================
// Phase B2: all remaining v in one launch: V(v) = C4(v&15) * V(v>>4).
// schemeA: v in [32,512), 480 blocks.  schemeB: v in [32,128), 96 blocks.
// ============================================================================
__global__ __launch_bounds__(256) void pair_kernel(u16* TThp, u16* TTlp, u16* TNhp, u16* TNlp,
                                                   int schemeA) {
    __shared__ uint4 Mh[GR], Ml[GR];
    uint4* TTh = (uint4*)TThp; uint4* TTl = (uint4*)TTlp;
    uint4* TNh = (uint4*)TNhp; uint4* TNl = (uint4*)TNlp;
    int v = 32 + blockIdx.x;
    int c4 = v & 15;
    int tnb = schemeA ? (2 + c4) : (14 + c4);          // slot of N(V(16+c4))
    int tta = (v >> 4) - 2;                            // slot of T(V(v>>4))
    f32x4 acc[4][4] = {};
    mm2<false>(TTh + (size_t)tta * GR, TTl + (size_t)tta * GR,
               TNh + (size_t)tnb * GR, TNl + (size_t)tnb * GR, acc);
    bool wN = schemeA ? (v >= 256) : true;
    bool wT = schemeA ? (v < 256) : true;
    if (wN) {
        int tn = schemeA ? (18 + (v - 256)) : (v - 2);
        acc_to_gN(acc, TNh + (size_t)tn * GR, TNl + (size_t)tn * GR);
    }
    if (wT) {
        acc_to_lds2(acc, Mh, Ml);
        __syncthreads();
        copyT(Mh, Ml, TTh + (size_t)(v - 2) * GR, TTl + (size_t)(v - 2) * GR);
    }
}

// ============================================================================
// Phase C: one block per position.
// schemeA: maps(p) = C8(p&255) * V(p>>8) -> ONE matmul, operands from global,
//          zero LDS.  schemeB: 6-bit chunks, <=2 matmuls, 64 KB dynamic LDS.
// ============================================================================
__global__ __launch_bounds__(256) void final_kernel(const u16* TThp, const u16* TTlp,
                                                    const u16* TNhp, const u16* TNlp,
                                                    const int* __restrict__ uq,
                                                    float* __restrict__ out, int schemeA) {
    extern __shared__ uint4 FL[];
    const uint4* TTh = (const uint4*)TThp; const uint4* TTl = (const uint4*)TTlp;
    const uint4* TNh = (const uint4*)TNhp; const uint4* TNl = (const uint4*)TNlp;
    float* O = out + (size_t)blockIdx.x * MAT;
    unsigned p = (unsigned)uq[blockIdx.x];

    if (p < 2u) {                                      // identity output
        for (int s = threadIdx.x; s < 4096; s += 256) {
            int r = s >> 5, c0 = (s & 31) * 4;
            float4 v; v.x = v.y = v.z = v.w = 0.f;
            int d = r - c0;
            if (d == 0) v.x = 1.f; else if (d == 1) v.y = 1.f;
            else if (d == 2) v.z = 1.f; else if (d == 3) v.w = 1.f;
            *(float4*)&O[r * DIM + c0] = v;
        }
        return;
    }

    const uint4 *pah, *pal, *pbh, *pbl;
    int m3 = -1;
    if (schemeA) {
        const int id = 274;
        if (p < 256u) {                                // out = V(p) * I
            pah = TTh + (size_t)(p - 2) * GR; pal = TTl + (size_t)(p - 2) * GR;
            pbh = TNh + (size_t)id * GR;      pbl = TNl + (size_t)id * GR;
        } else {
            int lo = (int)(p & 255u); unsigned hi = p >> 8;
            pbh = TNh + (size_t)(18 + lo) * GR; pbl = TNl + (size_t)(18 + lo) * GR;
            if (hi >= 2u) { pah = TTh + (size_t)(hi - 2) * GR; pal = TTl + (size_t)(hi - 2) * GR; }
            else          { pah = TNh + (size_t)id * GR;       pal = TNl + (size_t)id * GR; }
        }
    } else {
        int f[3]; int m = 0; unsigned q = p;
        while (q >= 128u) { f[m++] = 64 + (int)(q & 63u); q >>= 6; }
        f[m++] = (int)q;
        if (m == 1) {                                  // out = V(p) directly
            const uint4* sh = TNh + (size_t)(f[0] - 2) * GR;
            const uint4* sl = TNl + (size_t)(f[0] - 2) * GR;
            for (int s = threadIdx.x; s < GR; s += 256) {
                int row = s >> 4, g = s & 15;
                uint4 H = sh[g * 128 + row], L = sl[g * 128 + row];
                float4 o0, o1;
                o0.x = bf2f((u16)(H.x & 0xffff)) + bf2f((u16)(L.x & 0xffff));
                o0.y = bf2f((u16)(H.x >> 16))    + bf2f((u16)(L.x >> 16));
                o0.z = bf2f((u16)(H.y & 0xffff)) + bf2f((u16)(L.y & 0xffff));
                o0.w = bf2f((u16)(H.y >> 16))    + bf2f((u16)(L.y >> 16));
                o1.x = bf2f((u16)(H.z & 0xffff)) + bf2f((u16)(L.z & 0xffff));
                o1.y = bf2f((u16)(H.z >> 16))    + bf2f((u16)(L.z >> 16));
                o1.z = bf2f((u16)(H.w & 0xffff)) + bf2f((u16)(L.w & 0xffff));
                o1.w = bf2f((u16)(H.w >> 16))    + bf2f((u16)(L.w >> 16));
                *(float4*)&O[row * DIM + g * 8] = o0;
                *(float4*)&O[row * DIM + g * 8 + 4] = o1;
            }
            return;
        }
        pbh = TNh + (size_t)(f[0] - 2) * GR; pbl = TNl + (size_t)(f[0] - 2) * GR;
        pah = TTh + (size_t)(f[1] - 2) * GR; pal = TTl + (size_t)(f[1] - 2) * GR;
        if (m == 3) m3 = f[2] - 2;
    }

    f32x4 acc[4][4] = {};
    mm2<false>(pah, pal, pbh, pbl, acc);
    if (m3 < 0) { acc_to_out(acc, O); return; }
    acc_to_lds2(acc, FL, FL + GR);
    __syncthreads();
    f32x4 a2[4][4] = {};
    mm2<true>(TTh + (size_t)m3 * GR, TTl + (size_t)m3 * GR, FL, FL + GR, a2);
    acc_to_out(a2, O);
}

// ============================================================================
// launch
// ============================================================================
extern "C" void kernel_launch(void* const* d_in, const int* in_sizes, int n_in,
                              void* d_out, int out_size, void* d_ws, size_t ws_size,
                              hipStream_t stream) {
    const int*   uq = (const int*)d_in[0];
    const float* P  = (const float*)d_in[1];
    float* out = (float*)d_out;

    // scheme A (8/8 split, 1-matmul final) needs ~33.9 MiB; else 6-bit scheme (~16.6 MiB)
    const size_t needA = (size_t)(2 * 254 + 2 * 275 + 18) * MAT * 2 + (size_t)4 * MAT * 4;
    const bool A = ws_size >= needA;
    const int nTT = A ? 254 : 126;
    const int nTN = A ? 275 : 127;

    u16* TTh = (u16*)d_ws;
    u16* TTl = TTh + (size_t)nTT * MAT;
    u16* TNh = TTl + (size_t)nTT * MAT;
    u16* TNl = TNh + (size_t)nTN * MAT;
    u16* TB  = TNl + (size_t)nTN * MAT;     // [2][3][MAT]
    u16* TB3 = TB  + (size_t)6 * MAT;
    u16* XTg = TB3 + (size_t)6 * MAT;       // (retired scratch, kept for layout stability)
    float* NBf  = (float*)(XTg + (size_t)6 * MAT);
    float* NB2f = NBf + 2 * MAT;

    expm_kernel<<<2, 1024, 0, stream>>>(P, NBf, NB2f, TB, TB3, TTh, TTl, TNh, TNl);
    chain_kernel<<<29, 256, 0, stream>>>(TTh, TTl, TNh, TNl, (int)A);
    pair_kernel<<<A ? 480 : 96, 256, 0, stream>>>(TTh, TTl, TNh, TNl, (int)A);
    final_kernel<<<1024, 256, A ? 0 : 65536, stream>>>(TTh, TTl, TNh, TNl, uq, out, (int)A);
}

// Round 5
// 133.782 us; speedup vs baseline: 1.4093x; 1.0336x over previous
//
#include <hip/hip_runtime.h>

typedef unsigned int uint32;
typedef unsigned short u16;
typedef __attribute__((ext_vector_type(8))) short bf16x8;
typedef __attribute__((ext_vector_type(4))) float f32x4;
typedef __attribute__((ext_vector_type(2))) uint32 u32x2;
typedef __attribute__((ext_vector_type(4))) uint32 u32x4;

#define DIM 128
#define MAT (DIM * DIM)
#define GR  2048                 // uint4 granules per 128x128 bf16 plane (32 KB)
#define PLANE 16384              // u16 elements per plane
#define MFMA __builtin_amdgcn_mfma_f32_16x16x32_bf16

// Plane formats:
//  FmtG (global bf16 planes): uint4 granule index = g*128 + row   (g = col/8)
//  LDS standard (chain/pair/final + expm final staging): uint4 idx = row*16 + (g ^ (row&7))
//  LDS subtiled (expm internal, serves BOTH mfma operands):
//    element (r,c) at  ((r>>2)*8 + (c>>4))*64 + (r&3)*16 + (c&15)
//    - row fragment (fixed r, 8 consecutive c): contiguous 16 B  -> ds_read_b128
//    - col fragment (fixed c, consecutive r):   ds_read_b64_tr_b16.
//      tr_b16 semantics (verified round 3): result = column (addr>>3)&15 of the
//      4x16 row-major bf16 tile at (addr & ~127); so pass addr =
//      subtile_base_bytes + 8*col_in_subtile.
// Core semantic (verified): with a-frags from PA rows u and b-frags from PB
// rows w,  D[u][w] = sum_k PA[u][k]*PB[w][k]; the f32x4 acc spans 4
// consecutive u at fixed w.  For out = L*R: PA = T(R), PB = N(L), out[w][u]=D.
//
// Numerics (round 5): scale 1/32 + 5 squarings (||herm|| ~ 36 analytically:
// rank-2 skew dominates; deg-9 remainder at ||B||~1.14 is ~1e-6).  Squarings
// 2-split/3-pass (chain amplifies split error by 2^5=32 -- less than round 4's
// 2^6).  Taylor phases stay 3-split/6-pass.
// Squarings are DOUBLE-BUFFERED across plane pairs {0,1}<->{2,3}: mm reads src
// pair, epilogue writes dst pair, ONE barrier per phase (cross-wave hazards
// all separated by the previous barrier).  Final staging -> planes 2,3.

// ---------------- scalar helpers ----------------
__device__ __forceinline__ u16 f2bf(float x) {
    uint32 u = __float_as_uint(x);
    u += 0x7fffu + ((u >> 16) & 1u);
    return (u16)(u >> 16);
}
__device__ __forceinline__ float bf2f(u16 h) { return __uint_as_float(((uint32)h) << 16); }
__device__ __forceinline__ void split2(float x, u16& a0, u16& a1) {
    a0 = f2bf(x); a1 = f2bf(x - bf2f(a0));
}
__device__ __forceinline__ void split3(float x, u16& a0, u16& a1, u16& a2) {
    a0 = f2bf(x); float r = x - bf2f(a0);
    a1 = f2bf(r); float r2 = r - bf2f(a1);
    a2 = f2bf(r2);
}
__device__ __forceinline__ uint32 pack2(u16 a, u16 b) { return (uint32)a | ((uint32)b << 16); }
__device__ __forceinline__ uint4 packu4(const u16 (&a)[8]) {
    uint4 v; v.x = pack2(a[0], a[1]); v.y = pack2(a[2], a[3]);
    v.z = pack2(a[4], a[5]); v.w = pack2(a[6], a[7]); return v;
}
__device__ __forceinline__ uint32 comp4(const uint4& v, int c) {
    return c == 0 ? v.x : c == 1 ? v.y : c == 2 ? v.z : v.w;
}
// 8x8 u16 transpose in registers (all indices compile-time under unroll)
__device__ __forceinline__ void transp8(const uint4 (&in)[8], uint4 (&out)[8]) {
#pragma unroll
    for (int c = 0; c < 8; ++c) {
        u16 o[8];
#pragma unroll
        for (int k = 0; k < 8; ++k) o[k] = (u16)(comp4(in[k], c >> 1) >> ((c & 1) * 16));
        out[c].x = pack2(o[0], o[1]); out[c].y = pack2(o[2], o[3]);
        out[c].z = pack2(o[4], o[5]); out[c].w = pack2(o[6], o[7]);
    }
}

// ---------------- 4-wave (256 thr) 2-split 3-pass matmul core ----------------
template<bool PBLDS>
__device__ __forceinline__ void mm2(const uint4* __restrict__ pah, const uint4* __restrict__ pal,
                                    const uint4* __restrict__ pbh, const uint4* __restrict__ pbl,
                                    f32x4 (&acc)[4][4]) {
    const int tid = threadIdx.x, lane = tid & 63, w = tid >> 6;
    const int wr = (w >> 1) * 64, wc = (w & 1) * 64, lr = lane & 15, lg = lane >> 4;
#pragma unroll 1
    for (int kb = 0; kb < 4; ++kb) {
        const int g = kb * 4 + lg;
        bf16x8 ah[4], al[4], bh[4], bl[4];
#pragma unroll
        for (int t = 0; t < 4; ++t) {
            int ra = wr + t * 16 + lr;
            ah[t] = *(const bf16x8*)&pah[g * 128 + ra];
            al[t] = *(const bf16x8*)&pal[g * 128 + ra];
            int rb = wc + t * 16 + lr;
            int ib = PBLDS ? (rb * 16 + (g ^ (rb & 7))) : (g * 128 + rb);
            bh[t] = *(const bf16x8*)&pbh[ib];
            bl[t] = *(const bf16x8*)&pbl[ib];
        }
#pragma unroll
        for (int i = 0; i < 4; ++i)
#pragma unroll
            for (int j = 0; j < 4; ++j) {
                acc[i][j] = MFMA(ah[i], bh[j], acc[i][j], 0, 0, 0);
                acc[i][j] = MFMA(ah[i], bl[j], acc[i][j], 0, 0, 0);
                acc[i][j] = MFMA(al[i], bh[j], acc[i][j], 0, 0, 0);
            }
    }
}

// acc -> LDS pair (swizzled N-form: row w holds result[w][*])
__device__ __forceinline__ void acc_to_lds2(const f32x4 (&acc)[4][4], uint4* Mh, uint4* Ml) {
    const int tid = threadIdx.x, lane = tid & 63, w = tid >> 6;
    const int wr = (w >> 1) * 64, wc = (w & 1) * 64, lr = lane & 15, lg = lane >> 4;
#pragma unroll
    for (int i = 0; i < 4; ++i) {
        int u0 = wr + i * 16 + 4 * lg, half = (u0 >> 2) & 1, gq = u0 >> 3;
#pragma unroll
        for (int j = 0; j < 4; ++j) {
            int m = wc + j * 16 + lr;
            u16 h[4], l[4];
#pragma unroll
            for (int q = 0; q < 4; ++q) split2(acc[i][j][q], h[q], l[q]);
            uint2 hv; hv.x = pack2(h[0], h[1]); hv.y = pack2(h[2], h[3]);
            uint2 lv; lv.x = pack2(l[0], l[1]); lv.y = pack2(l[2], l[3]);
            int base = m * 16 + (gq ^ (m & 7));
            ((uint2*)&Mh[base])[half] = hv;
            ((uint2*)&Ml[base])[half] = lv;
        }
    }
}

// acc -> global FmtG pair (N-form rows)
__device__ __forceinline__ void acc_to_gN(const f32x4 (&acc)[4][4], uint4* nh, uint4* nl) {
    const int tid = threadIdx.x, lane = tid & 63, w = tid >> 6;
    const int wr = (w >> 1) * 64, wc = (w & 1) * 64, lr = lane & 15, lg = lane >> 4;
#pragma unroll
    for (int i = 0; i < 4; ++i) {
        int u0 = wr + i * 16 + 4 * lg, half = (u0 >> 2) & 1, gq = u0 >> 3;
#pragma unroll
        for (int j = 0; j < 4; ++j) {
            int m = wc + j * 16 + lr;
            u16 h[4], l[4];
#pragma unroll
            for (int q = 0; q < 4; ++q) split2(acc[i][j][q], h[q], l[q]);
            uint2 hv; hv.x = pack2(h[0], h[1]); hv.y = pack2(h[2], h[3]);
            uint2 lv; lv.x = pack2(l[0], l[1]); lv.y = pack2(l[2], l[3]);
            int base = gq * 128 + m;
            ((uint2*)&nh[base])[half] = hv;
            ((uint2*)&nl[base])[half] = lv;
        }
    }
}

// acc -> fp32 output (out[w][u])
__device__ __forceinline__ void acc_to_out(const f32x4 (&acc)[4][4], float* O) {
    const int tid = threadIdx.x, lane = tid & 63, w = tid >> 6;
    const int wr = (w >> 1) * 64, wc = (w & 1) * 64, lr = lane & 15, lg = lane >> 4;
#pragma unroll
    for (int i = 0; i < 4; ++i) {
        int u0 = wr + i * 16 + 4 * lg;
#pragma unroll
        for (int j = 0; j < 4; ++j) {
            int m = wc + j * 16 + lr;
            *(f32x4*)&O[m * DIM + u0] = acc[i][j];
        }
    }
}

// ---------------- plane copies ----------------
// global FmtG -> LDS swizzled (content preserved, N-form)
__device__ __forceinline__ void stage_lds(const uint4* sh, const uint4* sl, uint4* Mh, uint4* Ml) {
    for (int s = threadIdx.x; s < GR; s += blockDim.x) {
        int g = s >> 7, row = s & 127;
        int d = row * 16 + (g ^ (row & 7));
        Mh[d] = sh[s]; Ml[d] = sl[s];
    }
}
// LDS pair -> global FmtG pair, straight (N content)
__device__ __forceinline__ void copyN(const uint4* Mh, const uint4* Ml, uint4* dh, uint4* dl) {
    for (int s2 = threadIdx.x; s2 < 2 * GR; s2 += blockDim.x) {
        const uint4* src = (s2 & GR) ? Ml : Mh;
        uint4* dst = (s2 & GR) ? dl : dh;
        int s = s2 & (GR - 1);
        int g = s >> 7, row = s & 127;
        dst[s] = src[row * 16 + (g ^ (row & 7))];
    }
}
// LDS pair -> global FmtG pair, TRANSPOSED (dst[r][c] = src[c][r])
__device__ __forceinline__ void copyT(const uint4* Mh, const uint4* Ml, uint4* dh, uint4* dl) {
    for (int tk = threadIdx.x; tk < 512; tk += blockDim.x) {
        const uint4* src = (tk & 256) ? Ml : Mh;
        uint4* dst = (tk & 256) ? dl : dh;
        int t = tk & 255, br = t >> 4, bc = t & 15;
        uint4 in[8], out[8];
#pragma unroll
        for (int k = 0; k < 8; ++k) { int r = br * 8 + k; in[k] = src[r * 16 + (bc ^ (r & 7))]; }
        transp8(in, out);
#pragma unroll
        for (int k = 0; k < 8; ++k) dst[br * 128 + bc * 8 + k] = out[k];
    }
}

// ============================================================================
// Phase A: fused expm.  2 blocks x 1024 threads (16 waves, wave grid u:4 x w:4,
// 2x2 output tiles per wave).
// B = (P-P^T)/32; PS deg-9 Taylor (B2,B3 + 2 Horner steps); 5 squarings.
// X lives in LDS in the 4x16-subtiled layout which serves BOTH operands:
// B-op fragments via contiguous ds_read_b128, A-op (transposed) fragments via
// hardware ds_read_b64_tr_b16 -- no T-form materialization, no global
// round-trip in the squaring loop.  Taylor phases 3-split/6-pass in-place
// (2 barriers); squarings 2-split/3-pass double-buffered (1 barrier).
// A-op for MM2..MM4 comes from once-written global FmtG scratch
// (TB = -B = B^T, TB3 = -B3 = B3^T by skewness).
// ============================================================================

// NSP-split write of one f32x4 quad (row m, cols u0..u0+3) into subtiled LDS
__device__ __forceinline__ void wlds3s(u16* XSu, int m, int u0, f32x4 v) {
    u16 a0[4], a1[4], a2[4];
#pragma unroll
    for (int q = 0; q < 4; ++q) split3(v[q], a0[q], a1[q], a2[q]);
    int e = ((m >> 2) * 8 + (u0 >> 4)) * 64 + (m & 3) * 16 + (u0 & 15);
    uint2 w0; w0.x = pack2(a0[0], a0[1]); w0.y = pack2(a0[2], a0[3]);
    uint2 w1; w1.x = pack2(a1[0], a1[1]); w1.y = pack2(a1[2], a1[3]);
    uint2 w2; w2.x = pack2(a2[0], a2[1]); w2.y = pack2(a2[2], a2[3]);
    *(uint2*)&XSu[0 * PLANE + e] = w0;
    *(uint2*)&XSu[1 * PLANE + e] = w1;
    *(uint2*)&XSu[2 * PLANE + e] = w2;
}
__device__ __forceinline__ void wlds2s(u16* XSu, int m, int u0, f32x4 v) {
    u16 a0[4], a1[4];
#pragma unroll
    for (int q = 0; q < 4; ++q) split2(v[q], a0[q], a1[q]);
    int e = ((m >> 2) * 8 + (u0 >> 4)) * 64 + (m & 3) * 16 + (u0 & 15);
    uint2 w0; w0.x = pack2(a0[0], a0[1]); w0.y = pack2(a0[2], a0[3]);
    uint2 w1; w1.x = pack2(a1[0], a1[1]); w1.y = pack2(a1[2], a1[3]);
    *(uint2*)&XSu[0 * PLANE + e] = w0;
    *(uint2*)&XSu[1 * PLANE + e] = w1;
}

// 16-wave NSP-split matmul core.  ATR: A-op via ds_read_b64_tr_b16 from
// subtiled LDS (PA = T(X)); else A-op from global FmtG (pa).  B-op always
// subtiled LDS.  NSP==3: 6-pass (hh,hm,mh,mm,hl,lh); NSP==2: 3-pass (hh,hl,lh).
template<bool ATR, int NSP>
__device__ __forceinline__ void mmS(const uint4* __restrict__ pa, const u16* __restrict__ XSu,
                                    f32x4 (&acc)[2][2], int wr, int wc, int lr, int lg) {
#pragma unroll
    for (int i = 0; i < 2; ++i)
#pragma unroll
        for (int j = 0; j < 2; ++j) { f32x4 z = {0.f, 0.f, 0.f, 0.f}; acc[i][j] = z; }
    const uint32 lds_base = (uint32)(size_t)(const void*)XSu;
#pragma unroll 1
    for (int kb = 0; kb < 4; ++kb) {
        const int g = kb * 4 + lg;
        u32x2 t0[2][NSP], t1[2][NSP];
        bf16x8 aa[2][NSP], bb[2][NSP];
        if (ATR) {
            // column ra = wr + t*16 + lr of X, rows 8g..8g+7.
            // tile = subtile (16g + wr/16 + t) at byte (16g + wr/16 + t)*128;
            // column select = (addr>>3)&15 = lr  ->  addr = tile_base + 8*lr.
            // rows 4..7 live one subtile-row (8 subtiles = 1024 B) ahead.
#pragma unroll
            for (int t = 0; t < 2; ++t) {
                uint32 ba = lds_base + (uint32)(((16 * g + (wr >> 4) + t) << 7) + 8 * lr);
#pragma unroll
                for (int sp = 0; sp < NSP; ++sp) {
                    asm volatile("ds_read_b64_tr_b16 %0, %2\n\t"
                                 "ds_read_b64_tr_b16 %1, %2 offset:1024"
                                 : "=&v"(t0[t][sp]), "=&v"(t1[t][sp])
                                 : "v"(ba + (uint32)(sp * 2 * PLANE)));
                }
            }
        } else {
#pragma unroll
            for (int t = 0; t < 2; ++t) {
                int ra = wr + t * 16 + lr;
#pragma unroll
                for (int sp = 0; sp < NSP; ++sp) aa[t][sp] = *(const bf16x8*)&pa[sp * GR + g * 128 + ra];
            }
        }
#pragma unroll
        for (int t = 0; t < 2; ++t) {
            int rb = wc + t * 16 + lr;
            int e = ((rb >> 2) * 8 + (g >> 1)) * 64 + (rb & 3) * 16 + (g & 1) * 8;
#pragma unroll
            for (int sp = 0; sp < NSP; ++sp) bb[t][sp] = *(const bf16x8*)&XSu[sp * PLANE + e];
        }
        if (ATR) {
            // rule #18: drain asm ds_reads, then fence scheduling so the fragment
            // assembly + MFMAs cannot be hoisted above the wait.
            asm volatile("s_waitcnt lgkmcnt(0)" ::: "memory");
            __builtin_amdgcn_sched_barrier(0);
#pragma unroll
            for (int t = 0; t < 2; ++t)
#pragma unroll
                for (int sp = 0; sp < NSP; ++sp) {
                    u32x4 v; v.x = t0[t][sp].x; v.y = t0[t][sp].y;
                    v.z = t1[t][sp].x; v.w = t1[t][sp].y;
                    aa[t][sp] = *(bf16x8*)&v;
                }
        }
#pragma unroll
        for (int i = 0; i < 2; ++i)
#pragma unroll
            for (int j = 0; j < 2; ++j) {
                acc[i][j] = MFMA(aa[i][0], bb[j][0], acc[i][j], 0, 0, 0);
                acc[i][j] = MFMA(aa[i][0], bb[j][1], acc[i][j], 0, 0, 0);
                acc[i][j] = MFMA(aa[i][1], bb[j][0], acc[i][j], 0, 0, 0);
                if (NSP == 3) {
                    acc[i][j] = MFMA(aa[i][1], bb[j][1], acc[i][j], 0, 0, 0);
                    acc[i][j] = MFMA(aa[i][0], bb[j][2], acc[i][j], 0, 0, 0);
                    acc[i][j] = MFMA(aa[i][2], bb[j][0], acc[i][j], 0, 0, 0);
                }
            }
    }
}

__global__ __launch_bounds__(1024) void expm_kernel(
        const float* __restrict__ P, float* __restrict__ NBf, float* __restrict__ NB2f,
        u16* TBp, u16* TB3p,
        u16* TThp, u16* TTlp, u16* TNhp, u16* TNlp) {
    __shared__ uint4 XL[4 * GR];           // 128 KB (4 planes; squaring dbuf)
    u16* XSu = (u16*)XL;
    const int b = blockIdx.x, tid = threadIdx.x;
    const int lane = tid & 63, w = tid >> 6;
    const int wr = (w >> 2) * 32, wc = (w & 3) * 32, lr = lane & 15, lg = lane >> 4;
    const float* Pm = P + b * MAT;
    float* nbf = NBf + b * MAT;
    float* nb2f = NB2f + b * MAT;
    uint4* tb  = (uint4*)TBp  + (size_t)b * 3 * GR;
    uint4* tb3 = (uint4*)TB3p + (size_t)b * 3 * GR;
    uint4* TTh = (uint4*)TThp; uint4* TTl = (uint4*)TTlp;
    uint4* TNh = (uint4*)TNhp; uint4* TNl = (uint4*)TNlp;

    const float C6f = 1.0f / 720.0f, C7f = 1.0f / 5040.0f, C8f = 1.0f / 40320.0f, C9f = 1.0f / 362880.0f;

    // ---- prep: B = (P - P^T)/32 -> LDS(subtiled) + fp32 NBf + global TB (=-B, FmtG) ----
    for (int s = tid; s < GR; s += 1024) {
        int r = s >> 4, g = s & 15;
        float vv[8];
#pragma unroll
        for (int k = 0; k < 8; ++k) {
            int c = g * 8 + k;
            vv[k] = (Pm[r * DIM + c] - Pm[c * DIM + r]) * (1.0f / 32.0f);
        }
        float4 f0; f0.x = vv[0]; f0.y = vv[1]; f0.z = vv[2]; f0.w = vv[3];
        float4 f1; f1.x = vv[4]; f1.y = vv[5]; f1.z = vv[6]; f1.w = vv[7];
        *(float4*)&nbf[r * DIM + g * 8] = f0;
        *(float4*)&nbf[r * DIM + g * 8 + 4] = f1;
        u16 s0[8], s1[8], s2[8];
#pragma unroll
        for (int k = 0; k < 8; ++k) split3(vv[k], s0[k], s1[k], s2[k]);
        int d = ((r >> 2) * 8 + (g >> 1)) * 64 + (r & 3) * 16 + (g & 1) * 8;
        *(uint4*)&XSu[0 * PLANE + d] = packu4(s0);
        *(uint4*)&XSu[1 * PLANE + d] = packu4(s1);
        *(uint4*)&XSu[2 * PLANE + d] = packu4(s2);
        // negate by sign-flip
#pragma unroll
        for (int k = 0; k < 8; ++k) { s0[k] ^= 0x8000; s1[k] ^= 0x8000; s2[k] ^= 0x8000; }
        int gi = g * 128 + r;
        tb[0 * GR + gi] = packu4(s0); tb[1 * GR + gi] = packu4(s1); tb[2 * GR + gi] = packu4(s2);
    }
    __syncthreads();

    f32x4 acc[2][2];

    // ---- MM1: B2 = B*B  (A = T(B) via tr-reads) ----
    mmS<true, 3>(nullptr, XSu, acc, wr, wc, lr, lg);
    __syncthreads();
#pragma unroll
    for (int i = 0; i < 2; ++i) { int u0 = wr + i * 16 + 4 * lg;
#pragma unroll
        for (int j = 0; j < 2; ++j) { int m = wc + j * 16 + lr;
            *(f32x4*)&nb2f[m * DIM + u0] = acc[i][j];
            wlds3s(XSu, m, u0, acc[i][j]);
        } }
    __syncthreads();

    // ---- MM2: B3 = B2*B ; TB3 = -B3 ; X0 -> LDS ----
    mmS<false, 3>(tb, XSu, acc, wr, wc, lr, lg);
    __syncthreads();
#pragma unroll
    for (int i = 0; i < 2; ++i) { int u0 = wr + i * 16 + 4 * lg; int half = (u0 >> 2) & 1; int gi = (u0 >> 3) * 128;
#pragma unroll
        for (int j = 0; j < 2; ++j) { int m = wc + j * 16 + lr;
            f32x4 a = acc[i][j];
            u16 a0[4], a1[4], a2[4];
#pragma unroll
            for (int q = 0; q < 4; ++q) split3(-a[q], a0[q], a1[q], a2[q]);
            uint2 w0; w0.x = pack2(a0[0], a0[1]); w0.y = pack2(a0[2], a0[3]);
            uint2 w1; w1.x = pack2(a1[0], a1[1]); w1.y = pack2(a1[2], a1[3]);
            uint2 w2; w2.x = pack2(a2[0], a2[1]); w2.y = pack2(a2[2], a2[3]);
            ((uint2*)&tb3[0 * GR + gi + m])[half] = w0;
            ((uint2*)&tb3[1 * GR + gi + m])[half] = w1;
            ((uint2*)&tb3[2 * GR + gi + m])[half] = w2;
            f32x4 bv = *(const f32x4*)&nbf[m * DIM + u0];
            f32x4 b2v = *(const f32x4*)&nb2f[m * DIM + u0];
            f32x4 x0;
#pragma unroll
            for (int q = 0; q < 4; ++q)
                x0[q] = a[q] * C9f + b2v[q] * C8f + bv[q] * C7f + ((u0 + q == m) ? C6f : 0.0f);
            wlds3s(XSu, m, u0, x0);
        } }
    __syncthreads();

    // ---- MM3: X1 = X0*B3 + (I/6 + B/24 + B2/120) ----
    mmS<false, 3>(tb3, XSu, acc, wr, wc, lr, lg);
    __syncthreads();
#pragma unroll
    for (int i = 0; i < 2; ++i) { int u0 = wr + i * 16 + 4 * lg;
#pragma unroll
        for (int j = 0; j < 2; ++j) { int m = wc + j * 16 + lr;
            f32x4 bv = *(const f32x4*)&nbf[m * DIM + u0];
            f32x4 b2v = *(const f32x4*)&nb2f[m * DIM + u0];
            f32x4 x1;
#pragma unroll
            for (int q = 0; q < 4; ++q)
                x1[q] = acc[i][j][q] + bv[q] * (1.0f / 24.0f) + b2v[q] * (1.0f / 120.0f)
                      + ((u0 + q == m) ? (1.0f / 6.0f) : 0.0f);
            wlds3s(XSu, m, u0, x1);
        } }
    __syncthreads();

    // ---- MM4: X2 = X1*B3 + (I + B + B2/2) ----
    mmS<false, 3>(tb3, XSu, acc, wr, wc, lr, lg);
    __syncthreads();
#pragma unroll
    for (int i = 0; i < 2; ++i) { int u0 = wr + i * 16 + 4 * lg;
#pragma unroll
        for (int j = 0; j < 2; ++j) { int m = wc + j * 16 + lr;
            f32x4 bv = *(const f32x4*)&nbf[m * DIM + u0];
            f32x4 b2v = *(const f32x4*)&nb2f[m * DIM + u0];
            f32x4 x2;
#pragma unroll
            for (int q = 0; q < 4; ++q)
                x2[q] = acc[i][j][q] + bv[q] + b2v[q] * 0.5f + ((u0 + q == m) ? 1.0f : 0.0f);
            wlds3s(XSu, m, u0, x2);
        } }
    __syncthreads();

    // ---- 5 squarings, entirely in LDS, 2-split, double-buffered ----
    // sq even: read planes {0,1}, write {2,3}; sq odd: read {2,3}, write {0,1}.
    // Planes {0,1} of the 3-split X2 are exactly its 2-split (seamless entry).
    // One barrier per phase: per-wave order mm(src)->epilogue(dst)->barrier,
    // and the previous barrier separates all cross-wave read/write hazards.
    for (int sq = 0; sq < 5; ++sq) {
        const u16* src = XSu + ((sq & 1) ? 2 * PLANE : 0);
        u16* dst = XSu + ((sq & 1) ? 0 : 2 * PLANE);
        mmS<true, 2>(nullptr, src, acc, wr, wc, lr, lg);
        if (sq < 4) {
#pragma unroll
            for (int i = 0; i < 2; ++i) { int u0 = wr + i * 16 + 4 * lg;
#pragma unroll
                for (int j = 0; j < 2; ++j) wlds2s(dst, wc + j * 16 + lr, u0, acc[i][j]);
            }
            __syncthreads();
        } else {
            // sq==4 reads planes {0,1}; acc = exp(herm).  T_b = exp^T:
            // TT[b] = T(T_b) = exp (straight); TN[b] = N(T_b) = exp^T
            // (transposed).  2-split via standard-layout staging in planes
            // {2,3} (dbuf-safe), then copyN/copyT.
#pragma unroll
            for (int i = 0; i < 2; ++i) { int u0 = wr + i * 16 + 4 * lg; int half = (u0 >> 2) & 1;
#pragma unroll
                for (int j = 0; j < 2; ++j) { int m = wc + j * 16 + lr;
                    u16 h[4], l[4];
#pragma unroll
                    for (int q = 0; q < 4; ++q) split2(acc[i][j][q], h[q], l[q]);
                    uint2 hv; hv.x = pack2(h[0], h[1]); hv.y = pack2(h[2], h[3]);
                    uint2 lv; lv.x = pack2(l[0], l[1]); lv.y = pack2(l[2], l[3]);
                    int base = m * 16 + ((u0 >> 3) ^ (m & 7));
                    ((uint2*)&XL[2 * GR + base])[half] = hv;
                    ((uint2*)&XL[3 * GR + base])[half] = lv;
                } }
            __syncthreads();
            copyN(XL + 2 * GR, XL + 3 * GR, TTh + (size_t)b * GR, TTl + (size_t)b * GR);
            copyT(XL + 2 * GR, XL + 3 * GR, TNh + (size_t)b * GR, TNl + (size_t)b * GR);
        }
    }
}

// ============================================================================
// Phase B1: chains for v in [4,32) (+ identity plane).  29 blocks x 256 thr.
// V(v) = T_{b0} * T_{b1} * ... (bits LSB-first, leading 1 dropped).
// ============================================================================
__global__ __launch_bounds__(256) void chain_kernel(u16* TThp, u16* TTlp, u16* TNhp, u16* TNlp,
                                                    int schemeA) {
    __shared__ uint4 Mh[GR], Ml[GR];
    uint4* TTh = (uint4*)TThp; uint4* TTl = (uint4*)TTlp;
    uint4* TNh = (uint4*)TNhp; uint4* TNl = (uint4*)TNlp;
    int b = blockIdx.x;
    if (b == 28) {                           // identity N-plane
        int id = schemeA ? 274 : 126;
        for (int s = threadIdx.x; s < GR; s += 256) {
            int g = s >> 7, row = s & 127;
            u16 h[8];
#pragma unroll
            for (int k = 0; k < 8; ++k) h[k] = (g * 8 + k == row) ? (u16)0x3F80 : (u16)0;
            TNh[(size_t)id * GR + s] = packu4(h);
            uint4 z; z.x = z.y = z.z = z.w = 0u;
            TNl[(size_t)id * GR + s] = z;
        }
        return;
    }
    int v = 4 + b;
    int nb = 31 - __clz(v);                  // path length
    int b0 = v & 1;
    stage_lds(TNh + (size_t)b0 * GR, TNl + (size_t)b0 * GR, Mh, Ml);
    __syncthreads();
    for (int t = 1; t < nb; ++t) {
        int bt = (v >> t) & 1;
        f32x4 acc[4][4] = {};
        mm2<true>(TTh + (size_t)bt * GR, TTl + (size_t)bt * GR, Mh, Ml, acc);
        __syncthreads();
        acc_to_lds2(acc, Mh, Ml);
        __syncthreads();
    }
    copyT(Mh, Ml, TTh + (size_t)(v - 2) * GR, TTl + (size_t)(v - 2) * GR);
    bool needN = schemeA ? (v >= 16) : true;
    if (needN) {
        int tn = schemeA ? (v - 14) : (v - 2);
        copyN(Mh, Ml, TNh + (size_t)tn * GR, TNl + (size_t)tn * GR);
    }
}

// ============================================================================
// Phase B2: all remaining v in one launch: V(v) = C4(v&15) * V(v>>4).
// schemeA: v in [32,512), 480 blocks.  schemeB: v in [32,128), 96 blocks.
// ============================================================================
__global__ __launch_bounds__(256) void pair_kernel(u16* TThp, u16* TTlp, u16* TNhp, u16* TNlp,
                                                   int schemeA) {
    __shared__ uint4 Mh[GR], Ml[GR];
    uint4* TTh = (uint4*)TThp; uint4* TTl = (uint4*)TTlp;
    uint4* TNh = (uint4*)TNhp; uint4* TNl = (uint4*)TNlp;
    int v = 32 + blockIdx.x;
    int c4 = v & 15;
    int tnb = schemeA ? (2 + c4) : (14 + c4);          // slot of N(V(16+c4))
    int tta = (v >> 4) - 2;                            // slot of T(V(v>>4))
    f32x4 acc[4][4] = {};
    mm2<false>(TTh + (size_t)tta * GR, TTl + (size_t)tta * GR,
               TNh + (size_t)tnb * GR, TNl + (size_t)tnb * GR, acc);
    bool wN = schemeA ? (v >= 256) : true;
    bool wT = schemeA ? (v < 256) : true;
    if (wN) {
        int tn = schemeA ? (18 + (v - 256)) : (v - 2);
        acc_to_gN(acc, TNh + (size_t)tn * GR, TNl + (size_t)tn * GR);
    }
    if (wT) {
        acc_to_lds2(acc, Mh, Ml);
        __syncthreads();
        copyT(Mh, Ml, TTh + (size_t)(v - 2) * GR, TTl + (size_t)(v - 2) * GR);
    }
}

// ============================================================================
// Phase C: one block per position.
// schemeA: maps(p) = C8(p&255) * V(p>>8) -> ONE matmul, operands from global,
//          zero LDS.  schemeB: 6-bit chunks, <=2 matmuls, 64 KB dynamic LDS.
// ============================================================================
__global__ __launch_bounds__(256) void final_kernel(const u16* TThp, const u16* TTlp,
                                                    const u16* TNhp, const u16* TNlp,
                                                    const int* __restrict__ uq,
                                                    float* __restrict__ out, int schemeA) {
    extern __shared__ uint4 FL[];
    const uint4* TTh = (const uint4*)TThp; const uint4* TTl = (const uint4*)TTlp;
    const uint4* TNh = (const uint4*)TNhp; const uint4* TNl = (const uint4*)TNlp;
    float* O = out + (size_t)blockIdx.x * MAT;
    unsigned p = (unsigned)uq[blockIdx.x];

    if (p < 2u) {                                      // identity output
        for (int s = threadIdx.x; s < 4096; s += 256) {
            int r = s >> 5, c0 = (s & 31) * 4;
            float4 v; v.x = v.y = v.z = v.w = 0.f;
            int d = r - c0;
            if (d == 0) v.x = 1.f; else if (d == 1) v.y = 1.f;
            else if (d == 2) v.z = 1.f; else if (d == 3) v.w = 1.f;
            *(float4*)&O[r * DIM + c0] = v;
        }
        return;
    }

    const uint4 *pah, *pal, *pbh, *pbl;
    int m3 = -1;
    if (schemeA) {
        const int id = 274;
        if (p < 256u) {                                // out = V(p) * I
            pah = TTh + (size_t)(p - 2) * GR; pal = TTl + (size_t)(p - 2) * GR;
            pbh = TNh + (size_t)id * GR;      pbl = TNl + (size_t)id * GR;
        } else {
            int lo = (int)(p & 255u); unsigned hi = p >> 8;
            pbh = TNh + (size_t)(18 + lo) * GR; pbl = TNl + (size_t)(18 + lo) * GR;
            if (hi >= 2u) { pah = TTh + (size_t)(hi - 2) * GR; pal = TTl + (size_t)(hi - 2) * GR; }
            else          { pah = TNh + (size_t)id * GR;       pal = TNl + (size_t)id * GR; }
        }
    } else {
        int f[3]; int m = 0; unsigned q = p;
        while (q >= 128u) { f[m++] = 64 + (int)(q & 63u); q >>= 6; }
        f[m++] = (int)q;
        if (m == 1) {                                  // out = V(p) directly
            const uint4* sh = TNh + (size_t)(f[0] - 2) * GR;
            const uint4* sl = TNl + (size_t)(f[0] - 2) * GR;
            for (int s = threadIdx.x; s < GR; s += 256) {
                int row = s >> 4, g = s & 15;
                uint4 H = sh[g * 128 + row], L = sl[g * 128 + row];
                float4 o0, o1;
                o0.x = bf2f((u16)(H.x & 0xffff)) + bf2f((u16)(L.x & 0xffff));
                o0.y = bf2f((u16)(H.x >> 16))    + bf2f((u16)(L.x >> 16));
                o0.z = bf2f((u16)(H.y & 0xffff)) + bf2f((u16)(L.y & 0xffff));
                o0.w = bf2f((u16)(H.y >> 16))    + bf2f((u16)(L.y >> 16));
                o1.x = bf2f((u16)(H.z & 0xffff)) + bf2f((u16)(L.z & 0xffff));
                o1.y = bf2f((u16)(H.z >> 16))    + bf2f((u16)(L.z >> 16));
                o1.z = bf2f((u16)(H.w & 0xffff)) + bf2f((u16)(L.w & 0xffff));
                o1.w = bf2f((u16)(H.w >> 16))    + bf2f((u16)(L.w >> 16));
                *(float4*)&O[row * DIM + g * 8] = o0;
                *(float4*)&O[row * DIM + g * 8 + 4] = o1;
            }
            return;
        }
        pbh = TNh + (size_t)(f[0] - 2) * GR; pbl = TNl + (size_t)(f[0] - 2) * GR;
        pah = TTh + (size_t)(f[1] - 2) * GR; pal = TTl + (size_t)(f[1] - 2) * GR;
        if (m == 3) m3 = f[2] - 2;
    }

    f32x4 acc[4][4] = {};
    mm2<false>(pah, pal, pbh, pbl, acc);
    if (m3 < 0) { acc_to_out(acc, O); return; }
    acc_to_lds2(acc, FL, FL + GR);
    __syncthreads();
    f32x4 a2[4][4] = {};
    mm2<true>(TTh + (size_t)m3 * GR, TTl + (size_t)m3 * GR, FL, FL + GR, a2);
    acc_to_out(a2, O);
}

// ============================================================================
// launch
// ============================================================================
extern "C" void kernel_launch(void* const* d_in, const int* in_sizes, int n_in,
                              void* d_out, int out_size, void* d_ws, size_t ws_size,
                              hipStream_t stream) {
    const int*   uq = (const int*)d_in[0];
    const float* P  = (const float*)d_in[1];
    float* out = (float*)d_out;

    // scheme A (8/8 split, 1-matmul final) needs ~33.9 MiB; else 6-bit scheme (~16.6 MiB)
    const size_t needA = (size_t)(2 * 254 + 2 * 275 + 18) * MAT * 2 + (size_t)4 * MAT * 4;
    const bool A = ws_size >= needA;
    const int nTT = A ? 254 : 126;
    const int nTN = A ? 275 : 127;

    u16* TTh = (u16*)d_ws;
    u16* TTl = TTh + (size_t)nTT * MAT;
    u16* TNh = TTl + (size_t)nTT * MAT;
    u16* TNl = TNh + (size_t)nTN * MAT;
    u16* TB  = TNl + (size_t)nTN * MAT;     // [2][3][MAT]
    u16* TB3 = TB  + (size_t)6 * MAT;
    u16* XTg = TB3 + (size_t)6 * MAT;       // (retired scratch, kept for layout stability)
    float* NBf  = (float*)(XTg + (size_t)6 * MAT);
    float* NB2f = NBf + 2 * MAT;

    expm_kernel<<<2, 1024, 0, stream>>>(P, NBf, NB2f, TB, TB3, TTh, TTl, TNh, TNl);
    chain_kernel<<<29, 256, 0, stream>>>(TTh, TTl, TNh, TNl, (int)A);
    pair_kernel<<<A ? 480 : 96, 256, 0, stream>>>(TTh, TTl, TNh, TNl, (int)A);
    final_kernel<<<1024, 256, A ? 0 : 65536, stream>>>(TTh, TTl, TNh, TNl, uq, out, (int)A);
}

// Round 6
// 124.236 us; speedup vs baseline: 1.5176x; 1.0768x over previous
//
#include <hip/hip_runtime.h>

typedef unsigned int uint32;
typedef unsigned short u16;
typedef __attribute__((ext_vector_type(8))) short bf16x8;
typedef __attribute__((ext_vector_type(4))) float f32x4;
typedef __attribute__((ext_vector_type(2))) uint32 u32x2;
typedef __attribute__((ext_vector_type(4))) uint32 u32x4;

#define DIM 128
#define MAT (DIM * DIM)
#define GR  2048                 // uint4 granules per 128x128 bf16 plane (32 KB)
#define PLANE 16384              // u16 elements per plane
#define MFMA __builtin_amdgcn_mfma_f32_16x16x32_bf16

// Plane formats:
//  FmtG (global bf16 planes): uint4 granule index = g*128 + row   (g = col/8)
//  LDS standard (chain/pair/final + expm final staging): uint4 idx = row*16 + (g ^ (row&7))
//  LDS subtiled (expm internal, serves BOTH mfma operands):
//    element (r,c) at  ((r>>2)*8 + (c>>4))*64 + (r&3)*16 + (c&15)
//    - row fragment (fixed r, 8 consecutive c): contiguous 16 B  -> ds_read_b128
//    - col fragment (fixed c, consecutive r):   ds_read_b64_tr_b16.
//      tr_b16 semantics (verified round 3): result = column (addr>>3)&15 of the
//      4x16 row-major bf16 tile at (addr & ~127); so pass addr =
//      subtile_base_bytes + 8*col_in_subtile.
// Core semantic (verified): with a-frags from PA rows u and b-frags from PB
// rows w,  D[u][w] = sum_k PA[u][k]*PB[w][k]; the f32x4 acc spans 4
// consecutive u at fixed w.  For out = L*R: PA = T(R), PB = N(L), out[w][u]=D.
//
// Numerics (round 6): scale 1/32 + 5 squarings.  EVERYTHING 2-split/3-pass:
// measured evidence (rounds 4/5) shows split noise is not the absmax driver
// (2-split squarings left absmax at 0.0039).  Entry-wise B <= 1/32; split2
// operand error ~2^-17 relative, amplified 2^5 by squarings -> ~1e-5, far
// below the 0.019 threshold.  Missing ll pass ~2^-18 relative.
// The whole phase pipeline (MM1..MM4 + 5 squarings) strictly alternates LDS
// plane pairs {0,1} <-> {2,3}: each phase reads src pair, writes dst pair,
// ONE barrier per phase.  (Safe: writes to pair P in phase k+1 are separated
// from reads of P in phase k by the phase-k barrier.)

// ---------------- scalar helpers ----------------
__device__ __forceinline__ u16 f2bf(float x) {
    uint32 u = __float_as_uint(x);
    u += 0x7fffu + ((u >> 16) & 1u);
    return (u16)(u >> 16);
}
__device__ __forceinline__ float bf2f(u16 h) { return __uint_as_float(((uint32)h) << 16); }
__device__ __forceinline__ void split2(float x, u16& a0, u16& a1) {
    a0 = f2bf(x); a1 = f2bf(x - bf2f(a0));
}
__device__ __forceinline__ uint32 pack2(u16 a, u16 b) { return (uint32)a | ((uint32)b << 16); }
__device__ __forceinline__ uint4 packu4(const u16 (&a)[8]) {
    uint4 v; v.x = pack2(a[0], a[1]); v.y = pack2(a[2], a[3]);
    v.z = pack2(a[4], a[5]); v.w = pack2(a[6], a[7]); return v;
}
__device__ __forceinline__ uint32 comp4(const uint4& v, int c) {
    return c == 0 ? v.x : c == 1 ? v.y : c == 2 ? v.z : v.w;
}
// 8x8 u16 transpose in registers (all indices compile-time under unroll)
__device__ __forceinline__ void transp8(const uint4 (&in)[8], uint4 (&out)[8]) {
#pragma unroll
    for (int c = 0; c < 8; ++c) {
        u16 o[8];
#pragma unroll
        for (int k = 0; k < 8; ++k) o[k] = (u16)(comp4(in[k], c >> 1) >> ((c & 1) * 16));
        out[c].x = pack2(o[0], o[1]); out[c].y = pack2(o[2], o[3]);
        out[c].z = pack2(o[4], o[5]); out[c].w = pack2(o[6], o[7]);
    }
}

// ---------------- 4-wave (256 thr) 2-split 3-pass matmul core ----------------
template<bool PBLDS>
__device__ __forceinline__ void mm2(const uint4* __restrict__ pah, const uint4* __restrict__ pal,
                                    const uint4* __restrict__ pbh, const uint4* __restrict__ pbl,
                                    f32x4 (&acc)[4][4]) {
    const int tid = threadIdx.x, lane = tid & 63, w = tid >> 6;
    const int wr = (w >> 1) * 64, wc = (w & 1) * 64, lr = lane & 15, lg = lane >> 4;
#pragma unroll 1
    for (int kb = 0; kb < 4; ++kb) {
        const int g = kb * 4 + lg;
        bf16x8 ah[4], al[4], bh[4], bl[4];
#pragma unroll
        for (int t = 0; t < 4; ++t) {
            int ra = wr + t * 16 + lr;
            ah[t] = *(const bf16x8*)&pah[g * 128 + ra];
            al[t] = *(const bf16x8*)&pal[g * 128 + ra];
            int rb = wc + t * 16 + lr;
            int ib = PBLDS ? (rb * 16 + (g ^ (rb & 7))) : (g * 128 + rb);
            bh[t] = *(const bf16x8*)&pbh[ib];
            bl[t] = *(const bf16x8*)&pbl[ib];
        }
#pragma unroll
        for (int i = 0; i < 4; ++i)
#pragma unroll
            for (int j = 0; j < 4; ++j) {
                acc[i][j] = MFMA(ah[i], bh[j], acc[i][j], 0, 0, 0);
                acc[i][j] = MFMA(ah[i], bl[j], acc[i][j], 0, 0, 0);
                acc[i][j] = MFMA(al[i], bh[j], acc[i][j], 0, 0, 0);
            }
    }
}

// acc -> LDS pair (swizzled N-form: row w holds result[w][*])
__device__ __forceinline__ void acc_to_lds2(const f32x4 (&acc)[4][4], uint4* Mh, uint4* Ml) {
    const int tid = threadIdx.x, lane = tid & 63, w = tid >> 6;
    const int wr = (w >> 1) * 64, wc = (w & 1) * 64, lr = lane & 15, lg = lane >> 4;
#pragma unroll
    for (int i = 0; i < 4; ++i) {
        int u0 = wr + i * 16 + 4 * lg, half = (u0 >> 2) & 1, gq = u0 >> 3;
#pragma unroll
        for (int j = 0; j < 4; ++j) {
            int m = wc + j * 16 + lr;
            u16 h[4], l[4];
#pragma unroll
            for (int q = 0; q < 4; ++q) split2(acc[i][j][q], h[q], l[q]);
            uint2 hv; hv.x = pack2(h[0], h[1]); hv.y = pack2(h[2], h[3]);
            uint2 lv; lv.x = pack2(l[0], l[1]); lv.y = pack2(l[2], l[3]);
            int base = m * 16 + (gq ^ (m & 7));
            ((uint2*)&Mh[base])[half] = hv;
            ((uint2*)&Ml[base])[half] = lv;
        }
    }
}

// acc -> global FmtG pair (N-form rows)
__device__ __forceinline__ void acc_to_gN(const f32x4 (&acc)[4][4], uint4* nh, uint4* nl) {
    const int tid = threadIdx.x, lane = tid & 63, w = tid >> 6;
    const int wr = (w >> 1) * 64, wc = (w & 1) * 64, lr = lane & 15, lg = lane >> 4;
#pragma unroll
    for (int i = 0; i < 4; ++i) {
        int u0 = wr + i * 16 + 4 * lg, half = (u0 >> 2) & 1, gq = u0 >> 3;
#pragma unroll
        for (int j = 0; j < 4; ++j) {
            int m = wc + j * 16 + lr;
            u16 h[4], l[4];
#pragma unroll
            for (int q = 0; q < 4; ++q) split2(acc[i][j][q], h[q], l[q]);
            uint2 hv; hv.x = pack2(h[0], h[1]); hv.y = pack2(h[2], h[3]);
            uint2 lv; lv.x = pack2(l[0], l[1]); lv.y = pack2(l[2], l[3]);
            int base = gq * 128 + m;
            ((uint2*)&nh[base])[half] = hv;
            ((uint2*)&nl[base])[half] = lv;
        }
    }
}

// acc -> fp32 output (out[w][u])
__device__ __forceinline__ void acc_to_out(const f32x4 (&acc)[4][4], float* O) {
    const int tid = threadIdx.x, lane = tid & 63, w = tid >> 6;
    const int wr = (w >> 1) * 64, wc = (w & 1) * 64, lr = lane & 15, lg = lane >> 4;
#pragma unroll
    for (int i = 0; i < 4; ++i) {
        int u0 = wr + i * 16 + 4 * lg;
#pragma unroll
        for (int j = 0; j < 4; ++j) {
            int m = wc + j * 16 + lr;
            *(f32x4*)&O[m * DIM + u0] = acc[i][j];
        }
    }
}

// ---------------- plane copies ----------------
// global FmtG -> LDS swizzled (content preserved, N-form)
__device__ __forceinline__ void stage_lds(const uint4* sh, const uint4* sl, uint4* Mh, uint4* Ml) {
    for (int s = threadIdx.x; s < GR; s += blockDim.x) {
        int g = s >> 7, row = s & 127;
        int d = row * 16 + (g ^ (row & 7));
        Mh[d] = sh[s]; Ml[d] = sl[s];
    }
}
// LDS pair -> global FmtG pair, straight (N content)
__device__ __forceinline__ void copyN(const uint4* Mh, const uint4* Ml, uint4* dh, uint4* dl) {
    for (int s2 = threadIdx.x; s2 < 2 * GR; s2 += blockDim.x) {
        const uint4* src = (s2 & GR) ? Ml : Mh;
        uint4* dst = (s2 & GR) ? dl : dh;
        int s = s2 & (GR - 1);
        int g = s >> 7, row = s & 127;
        dst[s] = src[row * 16 + (g ^ (row & 7))];
    }
}
// LDS pair -> global FmtG pair, TRANSPOSED (dst[r][c] = src[c][r])
__device__ __forceinline__ void copyT(const uint4* Mh, const uint4* Ml, uint4* dh, uint4* dl) {
    for (int tk = threadIdx.x; tk < 512; tk += blockDim.x) {
        const uint4* src = (tk & 256) ? Ml : Mh;
        uint4* dst = (tk & 256) ? dl : dh;
        int t = tk & 255, br = t >> 4, bc = t & 15;
        uint4 in[8], out[8];
#pragma unroll
        for (int k = 0; k < 8; ++k) { int r = br * 8 + k; in[k] = src[r * 16 + (bc ^ (r & 7))]; }
        transp8(in, out);
#pragma unroll
        for (int k = 0; k < 8; ++k) dst[br * 128 + bc * 8 + k] = out[k];
    }
}

// ============================================================================
// Phase A: fused expm.  2 blocks x 1024 threads (16 waves, wave grid u:4 x w:4,
// 2x2 output tiles per wave).
// B = (P-P^T)/32; PS deg-9 Taylor (B2,B3 + 2 Horner steps); 5 squarings.
// X lives in LDS in the 4x16-subtiled layout which serves BOTH operands:
// B-op fragments via contiguous ds_read_b128, A-op (transposed) fragments via
// hardware ds_read_b64_tr_b16 -- no T-form materialization, no global
// round-trip anywhere in the phase pipeline.  ALL phases 2-split/3-pass and
// double-buffered across plane pairs {0,1}<->{2,3}: one barrier per phase.
// A-op for MM2..MM4 comes from once-written global FmtG scratch
// (TB = -B = B^T, TB3 = -B3 = B3^T by skewness), 2 planes each.
// ============================================================================

// 2-split write of one f32x4 quad (row m, cols u0..u0+3) into subtiled LDS pair
__device__ __forceinline__ void wlds2s(u16* dst, int m, int u0, f32x4 v) {
    u16 a0[4], a1[4];
#pragma unroll
    for (int q = 0; q < 4; ++q) split2(v[q], a0[q], a1[q]);
    int e = ((m >> 2) * 8 + (u0 >> 4)) * 64 + (m & 3) * 16 + (u0 & 15);
    uint2 w0; w0.x = pack2(a0[0], a0[1]); w0.y = pack2(a0[2], a0[3]);
    uint2 w1; w1.x = pack2(a1[0], a1[1]); w1.y = pack2(a1[2], a1[3]);
    *(uint2*)&dst[0 * PLANE + e] = w0;
    *(uint2*)&dst[1 * PLANE + e] = w1;
}

// 16-wave 2-split 3-pass matmul core.  ATR: A-op via ds_read_b64_tr_b16 from
// subtiled LDS src pair (PA = T(src)); else A-op from global FmtG (pa, 2
// planes).  B-op always subtiled LDS src pair.
template<bool ATR>
__device__ __forceinline__ void mmS(const uint4* __restrict__ pa, const u16* __restrict__ XSu,
                                    f32x4 (&acc)[2][2], int wr, int wc, int lr, int lg) {
#pragma unroll
    for (int i = 0; i < 2; ++i)
#pragma unroll
        for (int j = 0; j < 2; ++j) { f32x4 z = {0.f, 0.f, 0.f, 0.f}; acc[i][j] = z; }
    const uint32 lds_base = (uint32)(size_t)(const void*)XSu;
#pragma unroll 1
    for (int kb = 0; kb < 4; ++kb) {
        const int g = kb * 4 + lg;
        u32x2 t0[2][2], t1[2][2];
        bf16x8 aa[2][2], bb[2][2];
        if (ATR) {
            // column ra = wr + t*16 + lr of X, rows 8g..8g+7.
            // tile = subtile (16g + wr/16 + t) at byte (16g + wr/16 + t)*128;
            // column select = (addr>>3)&15 = lr  ->  addr = tile_base + 8*lr.
            // rows 4..7 live one subtile-row (8 subtiles = 1024 B) ahead.
#pragma unroll
            for (int t = 0; t < 2; ++t) {
                uint32 ba = lds_base + (uint32)(((16 * g + (wr >> 4) + t) << 7) + 8 * lr);
#pragma unroll
                for (int sp = 0; sp < 2; ++sp) {
                    asm volatile("ds_read_b64_tr_b16 %0, %2\n\t"
                                 "ds_read_b64_tr_b16 %1, %2 offset:1024"
                                 : "=&v"(t0[t][sp]), "=&v"(t1[t][sp])
                                 : "v"(ba + (uint32)(sp * 2 * PLANE)));
                }
            }
        } else {
#pragma unroll
            for (int t = 0; t < 2; ++t) {
                int ra = wr + t * 16 + lr;
#pragma unroll
                for (int sp = 0; sp < 2; ++sp) aa[t][sp] = *(const bf16x8*)&pa[sp * GR + g * 128 + ra];
            }
        }
#pragma unroll
        for (int t = 0; t < 2; ++t) {
            int rb = wc + t * 16 + lr;
            int e = ((rb >> 2) * 8 + (g >> 1)) * 64 + (rb & 3) * 16 + (g & 1) * 8;
#pragma unroll
            for (int sp = 0; sp < 2; ++sp) bb[t][sp] = *(const bf16x8*)&XSu[sp * PLANE + e];
        }
        if (ATR) {
            // rule #18: drain asm ds_reads, then fence scheduling so the fragment
            // assembly + MFMAs cannot be hoisted above the wait.
            asm volatile("s_waitcnt lgkmcnt(0)" ::: "memory");
            __builtin_amdgcn_sched_barrier(0);
#pragma unroll
            for (int t = 0; t < 2; ++t)
#pragma unroll
                for (int sp = 0; sp < 2; ++sp) {
                    u32x4 v; v.x = t0[t][sp].x; v.y = t0[t][sp].y;
                    v.z = t1[t][sp].x; v.w = t1[t][sp].y;
                    aa[t][sp] = *(bf16x8*)&v;
                }
        }
#pragma unroll
        for (int i = 0; i < 2; ++i)
#pragma unroll
            for (int j = 0; j < 2; ++j) {
                acc[i][j] = MFMA(aa[i][0], bb[j][0], acc[i][j], 0, 0, 0);
                acc[i][j] = MFMA(aa[i][0], bb[j][1], acc[i][j], 0, 0, 0);
                acc[i][j] = MFMA(aa[i][1], bb[j][0], acc[i][j], 0, 0, 0);
            }
    }
}

__global__ __launch_bounds__(1024) void expm_kernel(
        const float* __restrict__ P, float* __restrict__ NBf, float* __restrict__ NB2f,
        u16* TBp, u16* TB3p,
        u16* TThp, u16* TTlp, u16* TNhp, u16* TNlp) {
    __shared__ uint4 XL[4 * GR];           // 128 KB (2 plane pairs; full dbuf)
    u16* XSu = (u16*)XL;
    u16* PR0 = XSu;                        // pair {0,1}
    u16* PR1 = XSu + 2 * PLANE;            // pair {2,3}
    const int b = blockIdx.x, tid = threadIdx.x;
    const int lane = tid & 63, w = tid >> 6;
    const int wr = (w >> 2) * 32, wc = (w & 3) * 32, lr = lane & 15, lg = lane >> 4;
    const float* Pm = P + b * MAT;
    float* nbf = NBf + b * MAT;
    float* nb2f = NB2f + b * MAT;
    uint4* tb  = (uint4*)TBp  + (size_t)b * 3 * GR;
    uint4* tb3 = (uint4*)TB3p + (size_t)b * 3 * GR;
    uint4* TTh = (uint4*)TThp; uint4* TTl = (uint4*)TTlp;
    uint4* TNh = (uint4*)TNhp; uint4* TNl = (uint4*)TNlp;

    const float C6f = 1.0f / 720.0f, C7f = 1.0f / 5040.0f, C8f = 1.0f / 40320.0f, C9f = 1.0f / 362880.0f;

    // ---- prep: B = (P - P^T)/32 -> LDS pair {0,1} + fp32 NBf + global TB (=-B) ----
    for (int s = tid; s < GR; s += 1024) {
        int r = s >> 4, g = s & 15;
        float vv[8];
#pragma unroll
        for (int k = 0; k < 8; ++k) {
            int c = g * 8 + k;
            vv[k] = (Pm[r * DIM + c] - Pm[c * DIM + r]) * (1.0f / 32.0f);
        }
        float4 f0; f0.x = vv[0]; f0.y = vv[1]; f0.z = vv[2]; f0.w = vv[3];
        float4 f1; f1.x = vv[4]; f1.y = vv[5]; f1.z = vv[6]; f1.w = vv[7];
        *(float4*)&nbf[r * DIM + g * 8] = f0;
        *(float4*)&nbf[r * DIM + g * 8 + 4] = f1;
        u16 s0[8], s1[8];
#pragma unroll
        for (int k = 0; k < 8; ++k) split2(vv[k], s0[k], s1[k]);
        int d = ((r >> 2) * 8 + (g >> 1)) * 64 + (r & 3) * 16 + (g & 1) * 8;
        *(uint4*)&PR0[0 * PLANE + d] = packu4(s0);
        *(uint4*)&PR0[1 * PLANE + d] = packu4(s1);
        // negate by sign-flip
#pragma unroll
        for (int k = 0; k < 8; ++k) { s0[k] ^= 0x8000; s1[k] ^= 0x8000; }
        int gi = g * 128 + r;
        tb[0 * GR + gi] = packu4(s0); tb[1 * GR + gi] = packu4(s1);
    }
    __syncthreads();

    f32x4 acc[2][2];

    // ---- MM1: B2 = B*B  (A = T(B) tr-reads; src {0,1} -> dst {2,3}) ----
    mmS<true>(nullptr, PR0, acc, wr, wc, lr, lg);
#pragma unroll
    for (int i = 0; i < 2; ++i) { int u0 = wr + i * 16 + 4 * lg;
#pragma unroll
        for (int j = 0; j < 2; ++j) { int m = wc + j * 16 + lr;
            *(f32x4*)&nb2f[m * DIM + u0] = acc[i][j];
            wlds2s(PR1, m, u0, acc[i][j]);
        } }
    __syncthreads();

    // ---- MM2: B3 = B2*B ; TB3 = -B3 ; X0 (src {2,3} -> dst {0,1}) ----
    mmS<false>(tb, PR1, acc, wr, wc, lr, lg);
#pragma unroll
    for (int i = 0; i < 2; ++i) { int u0 = wr + i * 16 + 4 * lg; int half = (u0 >> 2) & 1; int gi = (u0 >> 3) * 128;
#pragma unroll
        for (int j = 0; j < 2; ++j) { int m = wc + j * 16 + lr;
            f32x4 a = acc[i][j];
            u16 a0[4], a1[4];
#pragma unroll
            for (int q = 0; q < 4; ++q) split2(-a[q], a0[q], a1[q]);
            uint2 w0; w0.x = pack2(a0[0], a0[1]); w0.y = pack2(a0[2], a0[3]);
            uint2 w1; w1.x = pack2(a1[0], a1[1]); w1.y = pack2(a1[2], a1[3]);
            ((uint2*)&tb3[0 * GR + gi + m])[half] = w0;
            ((uint2*)&tb3[1 * GR + gi + m])[half] = w1;
            f32x4 bv = *(const f32x4*)&nbf[m * DIM + u0];
            f32x4 b2v = *(const f32x4*)&nb2f[m * DIM + u0];
            f32x4 x0;
#pragma unroll
            for (int q = 0; q < 4; ++q)
                x0[q] = a[q] * C9f + b2v[q] * C8f + bv[q] * C7f + ((u0 + q == m) ? C6f : 0.0f);
            wlds2s(PR0, m, u0, x0);
        } }
    __syncthreads();

    // ---- MM3: X1 = X0*B3 + (I/6 + B/24 + B2/120)  (src {0,1} -> dst {2,3}) ----
    mmS<false>(tb3, PR0, acc, wr, wc, lr, lg);
#pragma unroll
    for (int i = 0; i < 2; ++i) { int u0 = wr + i * 16 + 4 * lg;
#pragma unroll
        for (int j = 0; j < 2; ++j) { int m = wc + j * 16 + lr;
            f32x4 bv = *(const f32x4*)&nbf[m * DIM + u0];
            f32x4 b2v = *(const f32x4*)&nb2f[m * DIM + u0];
            f32x4 x1;
#pragma unroll
            for (int q = 0; q < 4; ++q)
                x1[q] = acc[i][j][q] + bv[q] * (1.0f / 24.0f) + b2v[q] * (1.0f / 120.0f)
                      + ((u0 + q == m) ? (1.0f / 6.0f) : 0.0f);
            wlds2s(PR1, m, u0, x1);
        } }
    __syncthreads();

    // ---- MM4: X2 = X1*B3 + (I + B + B2/2)  (src {2,3} -> dst {0,1}) ----
    mmS<false>(tb3, PR1, acc, wr, wc, lr, lg);
#pragma unroll
    for (int i = 0; i < 2; ++i) { int u0 = wr + i * 16 + 4 * lg;
#pragma unroll
        for (int j = 0; j < 2; ++j) { int m = wc + j * 16 + lr;
            f32x4 bv = *(const f32x4*)&nbf[m * DIM + u0];
            f32x4 b2v = *(const f32x4*)&nb2f[m * DIM + u0];
            f32x4 x2;
#pragma unroll
            for (int q = 0; q < 4; ++q)
                x2[q] = acc[i][j][q] + bv[q] + b2v[q] * 0.5f + ((u0 + q == m) ? 1.0f : 0.0f);
            wlds2s(PR0, m, u0, x2);
        } }
    __syncthreads();

    // ---- 5 squarings, entirely in LDS, 2-split, double-buffered ----
    // sq even: src {0,1} -> dst {2,3}; sq odd: src {2,3} -> dst {0,1}.
    for (int sq = 0; sq < 5; ++sq) {
        const u16* src = (sq & 1) ? PR1 : PR0;
        u16* dst = (sq & 1) ? PR0 : PR1;
        mmS<true>(nullptr, src, acc, wr, wc, lr, lg);
        if (sq < 4) {
#pragma unroll
            for (int i = 0; i < 2; ++i) { int u0 = wr + i * 16 + 4 * lg;
#pragma unroll
                for (int j = 0; j < 2; ++j) wlds2s(dst, wc + j * 16 + lr, u0, acc[i][j]);
            }
            __syncthreads();
        } else {
            // sq==4 reads {0,1}; acc = exp(herm).  T_b = exp^T:
            // TT[b] = T(T_b) = exp (straight); TN[b] = N(T_b) = exp^T
            // (transposed).  2-split via standard-layout staging in planes
            // {2,3} (dbuf-safe), then copyN/copyT.
#pragma unroll
            for (int i = 0; i < 2; ++i) { int u0 = wr + i * 16 + 4 * lg; int half = (u0 >> 2) & 1;
#pragma unroll
                for (int j = 0; j < 2; ++j) { int m = wc + j * 16 + lr;
                    u16 h[4], l[4];
#pragma unroll
                    for (int q = 0; q < 4; ++q) split2(acc[i][j][q], h[q], l[q]);
                    uint2 hv; hv.x = pack2(h[0], h[1]); hv.y = pack2(h[2], h[3]);
                    uint2 lv; lv.x = pack2(l[0], l[1]); lv.y = pack2(l[2], l[3]);
                    int base = m * 16 + ((u0 >> 3) ^ (m & 7));
                    ((uint2*)&XL[2 * GR + base])[half] = hv;
                    ((uint2*)&XL[3 * GR + base])[half] = lv;
                } }
            __syncthreads();
            copyN(XL + 2 * GR, XL + 3 * GR, TTh + (size_t)b * GR, TTl + (size_t)b * GR);
            copyT(XL + 2 * GR, XL + 3 * GR, TNh + (size_t)b * GR, TNl + (size_t)b * GR);
        }
    }
}

// ============================================================================
// Phase B1: chains for v in [4,32) (+ identity plane).  29 blocks x 256 thr.
// V(v) = T_{b0} * T_{b1} * ... (bits LSB-first, leading 1 dropped).
// ============================================================================
__global__ __launch_bounds__(256) void chain_kernel(u16* TThp, u16* TTlp, u16* TNhp, u16* TNlp,
                                                    int schemeA) {
    __shared__ uint4 Mh[GR], Ml[GR];
    uint4* TTh = (uint4*)TThp; uint4* TTl = (uint4*)TTlp;
    uint4* TNh = (uint4*)TNhp; uint4* TNl = (uint4*)TNlp;
    int b = blockIdx.x;
    if (b == 28) {                           // identity N-plane
        int id = schemeA ? 274 : 126;
        for (int s = threadIdx.x; s < GR; s += 256) {
            int g = s >> 7, row = s & 127;
            u16 h[8];
#pragma unroll
            for (int k = 0; k < 8; ++k) h[k] = (g * 8 + k == row) ? (u16)0x3F80 : (u16)0;
            TNh[(size_t)id * GR + s] = packu4(h);
            uint4 z; z.x = z.y = z.z = z.w = 0u;
            TNl[(size_t)id * GR + s] = z;
        }
        return;
    }
    int v = 4 + b;
    int nb = 31 - __clz(v);                  // path length
    int b0 = v & 1;
    stage_lds(TNh + (size_t)b0 * GR, TNl + (size_t)b0 * GR, Mh, Ml);
    __syncthreads();
    for (int t = 1; t < nb; ++t) {
        int bt = (v >> t) & 1;
        f32x4 acc[4][4] = {};
        mm2<true>(TTh + (size_t)bt * GR, TTl + (size_t)bt * GR, Mh, Ml, acc);
        __syncthreads();
        acc_to_lds2(acc, Mh, Ml);
        __syncthreads();
    }
    copyT(Mh, Ml, TTh + (size_t)(v - 2) * GR, TTl + (size_t)(v - 2) * GR);
    bool needN = schemeA ? (v >= 16) : true;
    if (needN) {
        int tn = schemeA ? (v - 14) : (v - 2);
        copyN(Mh, Ml, TNh + (size_t)tn * GR, TNl + (size_t)tn * GR);
    }
}

// ============================================================================
// Phase B2: all remaining v in one launch: V(v) = C4(v&15) * V(v>>4).
// schemeA: v in [32,512), 480 blocks.  schemeB: v in [32,128), 96 blocks.
// ============================================================================
__global__ __launch_bounds__(256) void pair_kernel(u16* TThp, u16* TTlp, u16* TNhp, u16* TNlp,
                                                   int schemeA) {
    __shared__ uint4 Mh[GR], Ml[GR];
    uint4* TTh = (uint4*)TThp; uint4* TTl = (uint4*)TTlp;
    uint4* TNh = (uint4*)TNhp; uint4* TNl = (uint4*)TNlp;
    int v = 32 + blockIdx.x;
    int c4 = v & 15;
    int tnb = schemeA ? (2 + c4) : (14 + c4);          // slot of N(V(16+c4))
    int tta = (v >> 4) - 2;                            // slot of T(V(v>>4))
    f32x4 acc[4][4] = {};
    mm2<false>(TTh + (size_t)tta * GR, TTl + (size_t)tta * GR,
               TNh + (size_t)tnb * GR, TNl + (size_t)tnb * GR, acc);
    bool wN = schemeA ? (v >= 256) : true;
    bool wT = schemeA ? (v < 256) : true;
    if (wN) {
        int tn = schemeA ? (18 + (v - 256)) : (v - 2);
        acc_to_gN(acc, TNh + (size_t)tn * GR, TNl + (size_t)tn * GR);
    }
    if (wT) {
        acc_to_lds2(acc, Mh, Ml);
        __syncthreads();
        copyT(Mh, Ml, TTh + (size_t)(v - 2) * GR, TTl + (size_t)(v - 2) * GR);
    }
}

// ============================================================================
// Phase C: one block per position.
// schemeA: maps(p) = C8(p&255) * V(p>>8) -> ONE matmul, operands from global,
//          zero LDS.  schemeB: 6-bit chunks, <=2 matmuls, 64 KB dynamic LDS.
// ============================================================================
__global__ __launch_bounds__(256) void final_kernel(const u16* TThp, const u16* TTlp,
                                                    const u16* TNhp, const u16* TNlp,
                                                    const int* __restrict__ uq,
                                                    float* __restrict__ out, int schemeA) {
    extern __shared__ uint4 FL[];
    const uint4* TTh = (const uint4*)TThp; const uint4* TTl = (const uint4*)TTlp;
    const uint4* TNh = (const uint4*)TNhp; const uint4* TNl = (const uint4*)TNlp;
    float* O = out + (size_t)blockIdx.x * MAT;
    unsigned p = (unsigned)uq[blockIdx.x];

    if (p < 2u) {                                      // identity output
        for (int s = threadIdx.x; s < 4096; s += 256) {
            int r = s >> 5, c0 = (s & 31) * 4;
            float4 v; v.x = v.y = v.z = v.w = 0.f;
            int d = r - c0;
            if (d == 0) v.x = 1.f; else if (d == 1) v.y = 1.f;
            else if (d == 2) v.z = 1.f; else if (d == 3) v.w = 1.f;
            *(float4*)&O[r * DIM + c0] = v;
        }
        return;
    }

    const uint4 *pah, *pal, *pbh, *pbl;
    int m3 = -1;
    if (schemeA) {
        const int id = 274;
        if (p < 256u) {                                // out = V(p) * I
            pah = TTh + (size_t)(p - 2) * GR; pal = TTl + (size_t)(p - 2) * GR;
            pbh = TNh + (size_t)id * GR;      pbl = TNl + (size_t)id * GR;
        } else {
            int lo = (int)(p & 255u); unsigned hi = p >> 8;
            pbh = TNh + (size_t)(18 + lo) * GR; pbl = TNl + (size_t)(18 + lo) * GR;
            if (hi >= 2u) { pah = TTh + (size_t)(hi - 2) * GR; pal = TTl + (size_t)(hi - 2) * GR; }
            else          { pah = TNh + (size_t)id * GR;       pal = TNl + (size_t)id * GR; }
        }
    } else {
        int f[3]; int m = 0; unsigned q = p;
        while (q >= 128u) { f[m++] = 64 + (int)(q & 63u); q >>= 6; }
        f[m++] = (int)q;
        if (m == 1) {                                  // out = V(p) directly
            const uint4* sh = TNh + (size_t)(f[0] - 2) * GR;
            const uint4* sl = TNl + (size_t)(f[0] - 2) * GR;
            for (int s = threadIdx.x; s < GR; s += 256) {
                int row = s >> 4, g = s & 15;
                uint4 H = sh[g * 128 + row], L = sl[g * 128 + row];
                float4 o0, o1;
                o0.x = bf2f((u16)(H.x & 0xffff)) + bf2f((u16)(L.x & 0xffff));
                o0.y = bf2f((u16)(H.x >> 16))    + bf2f((u16)(L.x >> 16));
                o0.z = bf2f((u16)(H.y & 0xffff)) + bf2f((u16)(L.y & 0xffff));
                o0.w = bf2f((u16)(H.y >> 16))    + bf2f((u16)(L.y >> 16));
                o1.x = bf2f((u16)(H.z & 0xffff)) + bf2f((u16)(L.z & 0xffff));
                o1.y = bf2f((u16)(H.z >> 16))    + bf2f((u16)(L.z >> 16));
                o1.z = bf2f((u16)(H.w & 0xffff)) + bf2f((u16)(L.w & 0xffff));
                o1.w = bf2f((u16)(H.w >> 16))    + bf2f((u16)(L.w >> 16));
                *(float4*)&O[row * DIM + g * 8] = o0;
                *(float4*)&O[row * DIM + g * 8 + 4] = o1;
            }
            return;
        }
        pbh = TNh + (size_t)(f[0] - 2) * GR; pbl = TNl + (size_t)(f[0] - 2) * GR;
        pah = TTh + (size_t)(f[1] - 2) * GR; pal = TTl + (size_t)(f[1] - 2) * GR;
        if (m == 3) m3 = f[2] - 2;
    }

    f32x4 acc[4][4] = {};
    mm2<false>(pah, pal, pbh, pbl, acc);
    if (m3 < 0) { acc_to_out(acc, O); return; }
    acc_to_lds2(acc, FL, FL + GR);
    __syncthreads();
    f32x4 a2[4][4] = {};
    mm2<true>(TTh + (size_t)m3 * GR, TTl + (size_t)m3 * GR, FL, FL + GR, a2);
    acc_to_out(a2, O);
}

// ============================================================================
// launch
// ============================================================================
extern "C" void kernel_launch(void* const* d_in, const int* in_sizes, int n_in,
                              void* d_out, int out_size, void* d_ws, size_t ws_size,
                              hipStream_t stream) {
    const int*   uq = (const int*)d_in[0];
    const float* P  = (const float*)d_in[1];
    float* out = (float*)d_out;

    // scheme A (8/8 split, 1-matmul final) needs ~33.9 MiB; else 6-bit scheme (~16.6 MiB)
    const size_t needA = (size_t)(2 * 254 + 2 * 275 + 18) * MAT * 2 + (size_t)4 * MAT * 4;
    const bool A = ws_size >= needA;
    const int nTT = A ? 254 : 126;
    const int nTN = A ? 275 : 127;

    u16* TTh = (u16*)d_ws;
    u16* TTl = TTh + (size_t)nTT * MAT;
    u16* TNh = TTl + (size_t)nTT * MAT;
    u16* TNl = TNh + (size_t)nTN * MAT;
    u16* TB  = TNl + (size_t)nTN * MAT;     // [2][3][MAT] (2 planes used)
    u16* TB3 = TB  + (size_t)6 * MAT;
    u16* XTg = TB3 + (size_t)6 * MAT;       // (retired scratch, kept for layout stability)
    float* NBf  = (float*)(XTg + (size_t)6 * MAT);
    float* NB2f = NBf + 2 * MAT;

    expm_kernel<<<2, 1024, 0, stream>>>(P, NBf, NB2f, TB, TB3, TTh, TTl, TNh, TNl);
    chain_kernel<<<29, 256, 0, stream>>>(TTh, TTl, TNh, TNl, (int)A);
    pair_kernel<<<A ? 480 : 96, 256, 0, stream>>>(TTh, TTl, TNh, TNl, (int)A);
    final_kernel<<<1024, 256, A ? 0 : 65536, stream>>>(TTh, TTl, TNh, TNl, uq, out, (int)A);
}